// Round 11
// baseline (5115.792 us; speedup 1.0000x reference)
//
#include <hip/hip_runtime.h>
#include <hip/hip_bf16.h>
#include <cstdio>
#include <math.h>

// ---------------------------------------------------------------------------
// StyleGANv2 generator forward. bf16 MFMA implicit-GEMM convolutions.
//   mod+demod conv == d[b,o] * conv(x * s'[b,i], w_shared); s' folded into the
//   producer epilogue so GEMM A-operand is a pure bf16 gather.
//   Up-conv: parity-decomposed, one template instantiation per class (PY,PX).
//   k_conv: 128x128 tile; TT taps x 8 chunks fully COMPILE-TIME unrolled into
//   one continuous pipeline, register prefetch depth 2 (ping-pong pa[g&1]),
//   crossing tap boundaries via two named A-pointer slots (apE/apO selected by
//   compile-time tap&1). R5/R9 lesson: runtime back-edges carrying prefetch
//   state spill to scratch; full unroll keeps everything in registers.
//   Raw s_barrier x2 per chunk; XOR-8 LDS slot swizzle (128B rows) -> 0 bank
//   conflicts, all b128 aligned. Blur: separable k1 x k1 (V then H pass).
// ---------------------------------------------------------------------------

static constexpr int NB = 32;
static constexpr float SQRT2F      = 1.41421356237309515f;
static constexpr float INV_SQRT512 = 0.04419417382415922f;   // 1/sqrt(512)
static constexpr float INV_SQRT4608= 0.014731391274719742f;  // 1/sqrt(512*9)

typedef __hip_bfloat16 bf16;
typedef __attribute__((ext_vector_type(8))) short bf16x8;
typedef __attribute__((ext_vector_type(4))) float f32x4;

__device__ __forceinline__ float lrelu_s2(float v){ return (v > 0.f ? v : 0.2f*v) * SQRT2F; }
__device__ __forceinline__ float bf_lo(unsigned u){ unsigned v = u << 16; return __builtin_bit_cast(float, v); }
__device__ __forceinline__ float bf_hi(unsigned u){ unsigned v = u & 0xffff0000u; return __builtin_bit_cast(float, v); }
__device__ __forceinline__ unsigned packbf2(float a, float b){
  bf16 ha = __float2bfloat16(a), hb = __float2bfloat16(b);
  unsigned short ra = __builtin_bit_cast(unsigned short, ha);
  unsigned short rb = __builtin_bit_cast(unsigned short, hb);
  return (unsigned)ra | ((unsigned)rb << 16);
}

// ---------------- mapping network: pixel_norm + 8x (512x512 lrelu) ----------
__global__ void k_mapping(const float* __restrict__ z, const float* __restrict__ mlp_w,
                          const float* __restrict__ mlp_b, float* __restrict__ wlat){
  __shared__ float xb[512], yb[512], red[256];
  int b = blockIdx.x, t = threadIdx.x;
  float z0 = z[b*512 + t], z1 = z[b*512 + t + 256];
  red[t] = z0*z0 + z1*z1;
  __syncthreads();
  for(int s = 128; s > 0; s >>= 1){ if(t < s) red[t] += red[t+s]; __syncthreads(); }
  float norm = sqrtf(red[0]) * INV_SQRT512;
  float inv = 1.f / (norm + 1e-6f);
  xb[t] = z0*inv; xb[t+256] = z1*inv;
  __syncthreads();
  for(int l = 0; l < 8; l++){
    const float* Wl = mlp_w + (size_t)l*512*512;
    const float* bl = mlp_b + l*512;
    for(int oo = 0; oo < 2; oo++){
      int o = t + oo*256;
      const float4* wr = (const float4*)(Wl + (size_t)o*512);
      float acc = 0.f;
      #pragma unroll 4
      for(int k = 0; k < 128; k++){
        float4 w4 = wr[k];
        acc += w4.x*xb[4*k] + w4.y*xb[4*k+1] + w4.z*xb[4*k+2] + w4.w*xb[4*k+3];
      }
      yb[o] = lrelu_s2(acc*INV_SQRT512 + bl[o]*0.01f);
    }
    __syncthreads();
    xb[t] = yb[t]; xb[t+256] = yb[t+256];
    __syncthreads();
  }
  wlat[b*512+t] = xb[t]; wlat[b*512+t+256] = xb[t+256];
}

// ---------------- styles: s' for 9 conv layers + 5 torgb layers -------------
__global__ void k_styles(const float* __restrict__ wlat,
                         const float* __restrict__ csw, const float* __restrict__ csb,
                         const float* __restrict__ tsw, const float* __restrict__ tsb,
                         float* __restrict__ s_conv, float* __restrict__ s_trgb){
  int gid = blockIdx.x*256 + threadIdx.x;        // 14*32*512 = 229376 exactly
  int l = gid >> 14;
  int b = (gid >> 9) & 31;
  int i = gid & 511;
  const float* row; float bias, wsc;
  if(l < 9){ row = csw + ((size_t)l*512 + i)*512; bias = csb[l*512+i]; wsc = INV_SQRT4608; }
  else     { int lt = l-9; row = tsw + ((size_t)lt*512 + i)*512; bias = tsb[lt*512+i]; wsc = INV_SQRT512; }
  const float4* r4 = (const float4*)row;
  const float4* w4 = (const float4*)(wlat + b*512);
  float acc = 0.f;
  #pragma unroll 4
  for(int k = 0; k < 128; k++){
    float4 a = w4[k], c = r4[k];
    acc += a.x*c.x + a.y*c.y + a.z*c.z + a.w*c.w;
  }
  float s = (acc*INV_SQRT512 + bias) * wsc;
  if(l < 9) s_conv[((size_t)l*32 + b)*512 + i] = s;
  else      s_trgb[((size_t)(l-9)*32 + b)*512 + i] = s;
}

// ---------------- fused: wsq[l,o,i] = sum w^2; wB[l][tap][o][i] = bf16(w) ----
__global__ void k_prep(const float* __restrict__ cw, float* __restrict__ wsq,
                       bf16* __restrict__ wB){
  int gid = blockIdx.x*256 + threadIdx.x;        // 9*512*512; (l,o,i)
  const float* p = cw + (size_t)gid*9;
  int l = gid >> 18;
  int oi = gid & 0x3ffff;                        // o*512 + i
  float v[9]; float a = 0.f;
  #pragma unroll
  for(int t = 0; t < 9; t++){ v[t] = p[t]; a += v[t]*v[t]; }
  wsq[gid] = a;
  #pragma unroll
  for(int tap = 0; tap < 9; tap++)
    wB[((size_t)(l*9 + tap) << 18) + oi] = __float2bfloat16(v[tap]);
}

// ---------------- demod d[l,b,o] ---------------------------------------------
__global__ void k_demod(const float* __restrict__ s_conv, const float* __restrict__ wsq,
                        float* __restrict__ d_conv){
  __shared__ float s2[512];
  int l = blockIdx.x/32, b = blockIdx.x%32, t = threadIdx.x;
  size_t base = ((size_t)l*32 + b)*512;
  float v0 = s_conv[base + t], v1 = s_conv[base + t + 256];
  s2[t] = v0*v0; s2[t+256] = v1*v1;
  __syncthreads();
  for(int oo = 0; oo < 2; oo++){
    int o = t + oo*256;
    const float4* wr = (const float4*)(wsq + ((size_t)l*512 + o)*512);
    float acc = 0.f;
    #pragma unroll 4
    for(int k = 0; k < 128; k++){
      float4 w = wr[k];
      acc += w.x*s2[4*k] + w.y*s2[4*k+1] + w.z*s2[4*k+2] + w.w*s2[4*k+3];
    }
    d_conv[base + o] = rsqrtf(acc + 1e-8f);
  }
}

// ---------------- torgb compensation ratio ----------------------------------
__global__ void k_ratio(const float* __restrict__ s_conv, const float* __restrict__ s_trgb,
                        float* __restrict__ rat){
  int gid = blockIdx.x*256 + threadIdx.x;        // 5*32*512 = 81920
  int lt = gid >> 14;
  if(lt >= 4){ rat[gid] = 1.0f; return; }
  int b = (gid >> 9) & 31;
  int i = gid & 511;
  int cl = 1 + 2*lt;                             // consuming conv layer
  float st = s_trgb[((size_t)lt*32 + b)*512 + i];
  float sc = s_conv[((size_t)cl*32 + b)*512 + i];
  rat[gid] = (sc != 0.f) ? st/sc : 0.f;
}

// ---------------- const input -> act0 (B,4,4,512) pre-scaled by s_conv[0] ----
__global__ void k_init(const float* __restrict__ ci, const float* __restrict__ s_conv,
                       bf16* __restrict__ act){
  int gid = blockIdx.x*256 + threadIdx.x;        // 32*16*512 = 262144
  int c = gid & 511; int px = (gid >> 9) & 15; int b = gid >> 13;
  act[gid] = __float2bfloat16(ci[c*16 + px] * s_conv[b*512 + c]);
}

// ---------------- main conv: MFMA implicit GEMM, compile-time pipeline -------
template<bool UP, int PY, int PX>
__global__ __launch_bounds__(256, 2)
void k_conv(const bf16* __restrict__ act, const bf16* __restrict__ wL,
            const float* __restrict__ dL, const float* __restrict__ noise,
            const float* __restrict__ nw_ptr, const float* __restrict__ ab,
            const float* __restrict__ sN, bf16* __restrict__ outp,
            int Hin, int Mblocks){
  constexpr int NDY = UP ? ((PY==0)?2:1) : 3;
  constexpr int NDX = UP ? ((PX==0)?2:1) : 3;
  constexpr int TT  = NDY*NDX;
  constexpr int GTOT = TT*8;                     // chunk count (K/64)

  // n-inner 1D grid + bijective XCD swizzle (gridDim.x is a multiple of 8)
  const int q8 = gridDim.x >> 3;
  const int swz = (blockIdx.x & 7)*q8 + (blockIdx.x >> 3);
  const int nb = swz & 3, mb = swz >> 2;
  if(mb >= Mblocks) return;
  const int mbase = mb*128, nbase = nb*128;

  const int OHy = UP ? (Hin + 1 - PY) : Hin;
  const int OHx = UP ? (Hin + 1 - PX) : Hin;
  const int pixN = OHy*OHx;
  const int Mtot = NB*pixN;
  if(mbase >= Mtot) return;

  // LDS: 128 rows x 64 shorts (128B). 16B slot s stored at s^(row&7).
  __shared__ short As[128*64];
  __shared__ short Bs[128*64];
  const int t = threadIdx.x;
  const int row  = t >> 1;                       // staging row 0..127
  const int half = t & 1;                        // 64B half of the row
  const int r7   = row & 7;

  int m = mbase + row;
  const bool mval = (m < Mtot);
  int mm = mval ? m : 0;
  const int gb = mm / pixN; int rem = mm % pixN;
  const int gY = rem / OHx, gX = rem % OHx;

  // wave fragment geometry (4 waves, 2x2 over 128x128)
  const int wid = t >> 6;
  const int mrow0 = (wid >> 1)*64;
  const int ncol0 = (wid & 1)*64;
  const int lr = t & 15;
  const int ks = (t & 63) >> 4;
  const int lr7 = lr & 7;
  const int sw0 = (ks ^ lr7)*8;
  const int sw1 = ((4 + ks) ^ lr7)*8;

  int wsl[4];
  #pragma unroll
  for(int j = 0; j < 4; j++) wsl[j] = ((half*4 + j) ^ r7)*8;

  f32x4 acc[4][4];
  #pragma unroll
  for(int i = 0; i < 4; i++)
    #pragma unroll
    for(int j = 0; j < 4; j++) acc[i][j] = (f32x4){0.f,0.f,0.f,0.f};

  const bf16* browB = wL + ((size_t)(nbase + row) << 9) + half*32;

  // A-pointer maker for tap slot ttc (ttc is compile-time after unroll)
  auto mkA = [&](int ttc, const bf16*& ap, bool& ok){
    int dy = UP ? ((PY==0) ? (ttc/NDX)*2 : 1) : ttc/3;
    int dx = UP ? ((PX==0) ? (ttc%NDX)*2 : 1) : ttc%3;
    int yy, xx;
    if(UP){ yy = gY - ((dy - PY) >> 1); xx = gX - ((dx - PX) >> 1); }
    else  { yy = gY + dy - 1;           xx = gX + dx - 1; }
    ok = mval && ((unsigned)yy < (unsigned)Hin) && ((unsigned)xx < (unsigned)Hin);
    ap = act + ((size_t)((gb*Hin + yy)*Hin + xx) << 9) + half*32;
  };
  auto tapOf = [](int ttc)->int{
    int dy = UP ? ((PY==0) ? (ttc/NDX)*2 : 1) : ttc/3;
    int dx = UP ? ((PX==0) ? (ttc%NDX)*2 : 1) : ttc%3;
    return dy*3 + dx;
  };

  // two named A-pointer slots, selected by compile-time (tap_slot & 1)
  const bf16 *apE = act, *apO = act; bool aokE = false, aokO = false;
  mkA(0, apE, aokE);

  // prologue: prefetch chunks 0 and 1 (both tap slot 0)
  uint4 pa[2][4], pb[2][4];
  {
    const bf16* b0 = browB + ((size_t)tapOf(0) << 18);
    #pragma unroll
    for(int j = 0; j < 4; j++){
      pa[0][j] = aokE ? *(const uint4*)(apE + j*8)      : make_uint4(0u,0u,0u,0u);
      pb[0][j] = *(const uint4*)(b0 + j*8);
      pa[1][j] = aokE ? *(const uint4*)(apE + 64 + j*8) : make_uint4(0u,0u,0u,0u);
      pb[1][j] = *(const uint4*)(b0 + 64 + j*8);
    }
  }

  #pragma unroll
  for(int g = 0; g < GTOT; g++){
    const int buf = g & 1;
    asm volatile("" ::: "memory");
    __builtin_amdgcn_s_barrier();                // prev chunk's LDS reads done
    #pragma unroll
    for(int j = 0; j < 4; j++){
      *(uint4*)&As[row*64 + wsl[j]] = pa[buf][j];
      *(uint4*)&Bs[row*64 + wsl[j]] = pb[buf][j];
    }
    // issue loads for chunk g+2 (crosses tap boundaries; all compile-time)
    if(g + 2 < GTOT){
      const int gn = g + 2;
      const int tn = gn >> 3;                    // tap slot of chunk gn
      const int koff = (gn & 7)*64;
      if((gn & 7) == 0){                         // entering a new tap slot
        if(tn & 1) mkA(tn, apO, aokO);
        else       mkA(tn, apE, aokE);
      }
      const bf16* ap = (tn & 1) ? apO : apE;
      const bool  ok = (tn & 1) ? aokO : aokE;
      const bf16* bp = browB + ((size_t)tapOf(tn) << 18) + koff;
      #pragma unroll
      for(int j = 0; j < 4; j++){
        pa[buf][j] = ok ? *(const uint4*)(ap + koff + j*8) : make_uint4(0u,0u,0u,0u);
        pb[buf][j] = *(const uint4*)(bp + j*8);
      }
    }
    asm volatile("s_waitcnt lgkmcnt(0)" ::: "memory");  // my LDS writes done
    __builtin_amdgcn_s_barrier();                // tile ready; loads in flight
    #pragma unroll
    for(int h = 0; h < 2; h++){
      const int swr = h ? sw1 : sw0;
      bf16x8 af[4], bfr[4];
      #pragma unroll
      for(int f = 0; f < 4; f++){
        af[f]  = *(const bf16x8*)&As[(mrow0 + f*16 + lr)*64 + swr];
        bfr[f] = *(const bf16x8*)&Bs[(ncol0 + f*16 + lr)*64 + swr];
      }
      #pragma unroll
      for(int mf = 0; mf < 4; mf++)
        #pragma unroll
        for(int nf = 0; nf < 4; nf++)
          acc[mf][nf] = __builtin_amdgcn_mfma_f32_16x16x32_bf16(af[mf], bfr[nf], acc[mf][nf], 0, 0, 0);
    }
  }

  // epilogue: C/D frag mapping col=lane&15, row=(lane>>4)*4+reg  [m89-verified]
  const float nwv = UP ? 0.f : *nw_ptr;
  const int U = 2*Hin + 1;
  #pragma unroll
  for(int mf = 0; mf < 4; mf++){
    #pragma unroll
    for(int r = 0; r < 4; r++){
      int me = mbase + mrow0 + mf*16 + ks*4 + r;
      if(me >= Mtot) continue;
      int b = me / pixN; int rem2 = me % pixN; int y = rem2 / OHx, x = rem2 % OHx;
      const float* drow = dL + b*512;
      bf16* orow;
      float nz = 0.f; const float* srow = nullptr;
      if(UP){
        orow = outp + (((size_t)((b*U + 2*y + PY))*U + (2*x + PX)) << 9);
      } else {
        nz = nwv * noise[(b*OHy + y)*OHx + x];
        srow = sN + b*512;
        orow = outp + ((size_t)me << 9);
      }
      #pragma unroll
      for(int nf = 0; nf < 4; nf++){
        int n = nbase + ncol0 + nf*16 + lr;
        float val = acc[mf][nf][r] * drow[n];
        if(!UP) val = lrelu_s2(val + nz + ab[n]) * srow[n];
        orow[n] = __float2bfloat16(val);
      }
    }
  }
}

// ---------------- separable blur: V pass (u -> tmp) --------------------------
__global__ void k_blurV(const bf16* __restrict__ u, bf16* __restrict__ tmp, int O){
  const int U = O + 1;
  size_t gid = (size_t)blockIdx.x*256 + threadIdx.x;
  size_t total = (size_t)NB*O*U*128;
  if(gid >= total) return;
  int c4 = gid & 127;
  size_t pix = gid >> 7;                         // (b*O + Y)*U + X
  int X = pix % U; int Y = (pix/U) % O; int b = pix/((size_t)O*U);
  const float k1[4] = {0.25f, 0.75f, 0.75f, 0.25f};
  float4 a = make_float4(0.f,0.f,0.f,0.f);
  #pragma unroll
  for(int ky = 0; ky < 4; ky++){
    int yy = Y + ky - 1; if(yy < 0 || yy >= U) continue;
    float w = k1[ky];
    uint2 u2 = *(const uint2*)(u + (((size_t)(b*U + yy)*U + X) << 9) + c4*4);
    a.x += w*bf_lo(u2.x); a.y += w*bf_hi(u2.x);
    a.z += w*bf_lo(u2.y); a.w += w*bf_hi(u2.y);
  }
  uint2 pk;
  pk.x = packbf2(a.x, a.y); pk.y = packbf2(a.z, a.w);
  *(uint2*)(tmp + (pix << 9) + c4*4) = pk;
}

// ------- separable blur: H pass + noise + bias + lrelu + next-scale ----------
__global__ void k_blurH(const bf16* __restrict__ tmp, const float* __restrict__ noise,
                        const float* __restrict__ nw_ptr, const float* __restrict__ ab,
                        const float* __restrict__ sN, bf16* __restrict__ act, int O){
  const int U = O + 1;
  size_t gid = (size_t)blockIdx.x*256 + threadIdx.x;
  size_t total = (size_t)NB*O*O*128;
  if(gid >= total) return;
  int c4 = gid & 127;
  size_t pix = gid >> 7;                         // (b*O + Y)*O + X
  int X = pix % O; int Y = (pix/O) % O; int b = pix/((size_t)O*O);
  const float k1[4] = {0.25f, 0.75f, 0.75f, 0.25f};
  float4 a = make_float4(0.f,0.f,0.f,0.f);
  #pragma unroll
  for(int kx = 0; kx < 4; kx++){
    int xx = X + kx - 1; if(xx < 0 || xx >= U) continue;
    float w = k1[kx];
    uint2 u2 = *(const uint2*)(tmp + (((size_t)(b*O + Y)*U + xx) << 9) + c4*4);
    a.x += w*bf_lo(u2.x); a.y += w*bf_hi(u2.x);
    a.z += w*bf_lo(u2.y); a.w += w*bf_hi(u2.y);
  }
  float nz = (*nw_ptr) * noise[(b*O + Y)*O + X];
  const float* abp4 = ab + c4*4;
  float4 s4 = *(const float4*)(sN + b*512 + c4*4);
  uint2 pk;
  pk.x = packbf2(lrelu_s2(a.x + nz + abp4[0])*s4.x, lrelu_s2(a.y + nz + abp4[1])*s4.y);
  pk.y = packbf2(lrelu_s2(a.z + nz + abp4[2])*s4.z, lrelu_s2(a.w + nz + abp4[3])*s4.w);
  *(uint2*)(act + (pix << 9) + c4*4) = pk;
}

// ---------------- toRGB (1x1 mod conv, no demod) -> NCHW skip ----------------
__global__ void k_torgb(const bf16* __restrict__ act, const float* __restrict__ tw,
                        const float* __restrict__ ratL, const float* __restrict__ tbias,
                        float* __restrict__ dst, int H, int lt, int addflag){
  int wid = threadIdx.x >> 6, lane = threadIdx.x & 63;
  int pix = blockIdx.x*4 + wid;
  int npix = NB*H*H;
  if(pix >= npix) return;
  int b = pix/(H*H);
  const bf16* ap = act + ((size_t)pix << 9);
  const float* rp = ratL + (size_t)b*512;
  const float* w0 = tw + ((size_t)lt*3 + 0)*512;
  const float* w1 = tw + ((size_t)lt*3 + 1)*512;
  const float* w2 = tw + ((size_t)lt*3 + 2)*512;
  float a0 = 0.f, a1 = 0.f, a2 = 0.f;
  #pragma unroll
  for(int j = 0; j < 8; j++){
    int i = lane + j*64;
    float xs = __bfloat162float(ap[i])*rp[i];
    a0 += xs*w0[i]; a1 += xs*w1[i]; a2 += xs*w2[i];
  }
  for(int off = 32; off > 0; off >>= 1){
    a0 += __shfl_xor(a0, off);
    a1 += __shfl_xor(a1, off);
    a2 += __shfl_xor(a2, off);
  }
  if(lane == 0){
    int rem = pix % (H*H);
    size_t o0 = ((size_t)(b*3 + 0)*H*H) + rem;
    size_t o1 = ((size_t)(b*3 + 1)*H*H) + rem;
    size_t o2 = ((size_t)(b*3 + 2)*H*H) + rem;
    float b0 = tbias[lt*3+0], b1 = tbias[lt*3+1], b2 = tbias[lt*3+2];
    if(addflag){ dst[o0] += a0 + b0; dst[o1] += a1 + b1; dst[o2] += a2 + b2; }
    else       { dst[o0]  = a0 + b0; dst[o1]  = a1 + b1; dst[o2]  = a2 + b2; }
  }
}

// ---------------- skip upsample 2x (NCHW, 3ch) -------------------------------
__global__ void k_skipup(const float* __restrict__ sin, float* __restrict__ sout, int h){
  const int O = 2*h;
  int gid = blockIdx.x*256 + threadIdx.x;
  int total = NB*3*O*O;
  if(gid >= total) return;
  int X = gid % O; int Y = (gid/O) % O; int c = (gid/(O*O)) % 3; int b = gid/(3*O*O);
  const float k1[4] = {1.f, 3.f, 3.f, 1.f};
  float acc = 0.f;
  for(int ky = (Y & 1); ky < 4; ky += 2){
    int ty = Y + ky - 2;
    if(ty < 0) continue;
    int y = ty >> 1; if(y >= h) continue;
    for(int kx = (X & 1); kx < 4; kx += 2){
      int tx = X + kx - 2;
      if(tx < 0) continue;
      int x = tx >> 1; if(x >= h) continue;
      acc += k1[ky]*k1[kx]*(1.f/16.f) * sin[((size_t)(b*3 + c)*h + y)*h + x];
    }
  }
  sout[gid] = acc;
}

// ---------------------------------------------------------------------------
extern "C" void kernel_launch(void* const* d_in, const int* in_sizes, int n_in,
                              void* d_out, int out_size, void* d_ws, size_t ws_size,
                              hipStream_t stream){
  const float* z     = (const float*)d_in[0];
  const float* mlp_w = (const float*)d_in[1];
  const float* mlp_b = (const float*)d_in[2];
  const float* cinp  = (const float*)d_in[3];
  const float* conv_w= (const float*)d_in[4];
  const float* csw   = (const float*)d_in[5];
  const float* csb   = (const float*)d_in[6];
  const float* nwp   = (const float*)d_in[7];
  const float* abp   = (const float*)d_in[8];
  const float* tw    = (const float*)d_in[9];
  const float* tsw   = (const float*)d_in[10];
  const float* tsb   = (const float*)d_in[11];
  const float* tb    = (const float*)d_in[12];
  const float* noise[9];
  for(int i = 0; i < 9; i++) noise[i] = (const float*)d_in[13 + i];

  // workspace layout (bytes)
  const size_t UMAX = (size_t)32*65*65*512;       // 69,206,016 elems
  char* base = (char*)d_ws;
  size_t off = 0;
  bf16* buf0 = (bf16*)(base + off); off += UMAX*2;                 // 138,412,032
  bf16* buf1 = (bf16*)(base + off); off += UMAX*2;                 // 138,412,032
  bf16* wB   = (bf16*)(base + off); off += (size_t)9*9*512*512*2;  //  42,467,328
  float* wsq = (float*)(base + off); off += (size_t)9*512*512*4;   //   9,437,184
  float* wlat= (float*)(base + off); off += (size_t)32*512*4;
  float* sconv=(float*)(base + off); off += (size_t)9*32*512*4;
  float* dconv=(float*)(base + off); off += (size_t)9*32*512*4;
  float* strgb=(float*)(base + off); off += (size_t)5*32*512*4;
  float* rat  =(float*)(base + off); off += (size_t)5*32*512*4;
  float* skipA=(float*)(base + off); off += (size_t)32*3*64*64*4;
  float* skipB=(float*)(base + off); off += (size_t)32*3*64*64*4;
  if(ws_size < off){
    fprintf(stderr, "kernel_launch: ws too small (%zu < %zu)\n", ws_size, off);
    return;
  }
  float* out = (float*)d_out;

  // prep
  k_mapping<<<32, 256, 0, stream>>>(z, mlp_w, mlp_b, wlat);
  k_styles <<<896, 256, 0, stream>>>(wlat, csw, csb, tsw, tsb, sconv, strgb);
  k_prep   <<<9216, 256, 0, stream>>>(conv_w, wsq, wB);
  k_demod  <<<288, 256, 0, stream>>>(sconv, wsq, dconv);
  k_ratio  <<<320, 256, 0, stream>>>(sconv, strgb, rat);
  k_init   <<<1024, 256, 0, stream>>>(cinp, sconv, buf0);

  auto conv_noup = [&](const bf16* in, bf16* o, int H, int layer, const float* sN){
    int M = 32*H*H; int Mb = (M + 127)/128;
    int Gx = ((Mb*4 + 7)/8)*8;
    k_conv<false,0,0><<<dim3(Gx,1,1), 256, 0, stream>>>(in, wB + ((size_t)layer*9 << 18),
        dconv + (size_t)layer*NB*512, noise[layer], nwp + layer, abp + layer*512, sN, o, H, Mb);
  };
  auto conv_up = [&](const bf16* in, bf16* o, int Hin, int layer){
    const bf16* w = wB + ((size_t)layer*9 << 18);
    const float* d = dconv + (size_t)layer*NB*512;
    auto gx = [&](int M){ int Mb = (M + 127)/128; return ((Mb*4 + 7)/8)*8; };
    int Ma = 32*(Hin+1)*(Hin+1), Mb_ = 32*(Hin+1)*Hin, Mc = 32*Hin*(Hin+1), Md = 32*Hin*Hin;
    k_conv<true,0,0><<<dim3(gx(Ma),1,1), 256, 0, stream>>>(in, w, d, nullptr, nullptr, nullptr, nullptr, o, Hin, (Ma+127)/128);
    k_conv<true,0,1><<<dim3(gx(Mb_),1,1), 256, 0, stream>>>(in, w, d, nullptr, nullptr, nullptr, nullptr, o, Hin, (Mb_+127)/128);
    k_conv<true,1,0><<<dim3(gx(Mc),1,1), 256, 0, stream>>>(in, w, d, nullptr, nullptr, nullptr, nullptr, o, Hin, (Mc+127)/128);
    k_conv<true,1,1><<<dim3(gx(Md),1,1), 256, 0, stream>>>(in, w, d, nullptr, nullptr, nullptr, nullptr, o, Hin, (Md+127)/128);
  };
  auto blur = [&](const bf16* u, bf16* tmp, bf16* o, int O, int layer, const float* sN){
    size_t totV = (size_t)32*O*(O+1)*128;
    size_t totH = (size_t)32*O*O*128;
    k_blurV<<<(unsigned)((totV + 255)/256), 256, 0, stream>>>(u, tmp, O);
    k_blurH<<<(unsigned)((totH + 255)/256), 256, 0, stream>>>(tmp, noise[layer], nwp + layer,
        abp + layer*512, sN, o, O);
  };
  auto torgb = [&](const bf16* act, float* dst, int H, int lt, int add){
    int npix = 32*H*H;
    k_torgb<<<(npix + 3)/4, 256, 0, stream>>>(act, tw, rat + (size_t)lt*NB*512, tb, dst, H, lt, add);
  };
  auto skipup = [&](const float* sin, float* sout, int h){
    int total = 32*3*(2*h)*(2*h);
    k_skipup<<<(total + 255)/256, 256, 0, stream>>>(sin, sout, h);
  };

  const float* S = sconv;   // s rows per layer: S + layer*NB*512
  const float* sT4 = strgb + (size_t)4*NB*512;

  // layer 0 @4   (buf0 = act0; output scaled by s1)
  conv_noup(buf0, buf1, 4, 0, S + (size_t)1*NB*512);   // buf0 -> buf1
  torgb(buf1, skipA, 4, 0, 0);

  // r=0: 4->8
  conv_up(buf1, buf0, 4, 1);                            // buf1 -> buf0 (u)
  blur(buf0, buf1, buf0, 8, 1, S + (size_t)2*NB*512);   // V: 0->1, H: 1->0 (act8)
  conv_noup(buf0, buf1, 8, 2, S + (size_t)3*NB*512);    // buf0 -> buf1
  skipup(skipA, skipB, 4);
  torgb(buf1, skipB, 8, 1, 1);

  // r=1: 8->16
  conv_up(buf1, buf0, 8, 3);
  blur(buf0, buf1, buf0, 16, 3, S + (size_t)4*NB*512);
  conv_noup(buf0, buf1, 16, 4, S + (size_t)5*NB*512);
  skipup(skipB, skipA, 8);
  torgb(buf1, skipA, 16, 2, 1);

  // r=2: 16->32
  conv_up(buf1, buf0, 16, 5);
  blur(buf0, buf1, buf0, 32, 5, S + (size_t)6*NB*512);
  conv_noup(buf0, buf1, 32, 6, S + (size_t)7*NB*512);
  skipup(skipA, skipB, 16);
  torgb(buf1, skipB, 32, 3, 1);

  // r=3: 32->64
  conv_up(buf1, buf0, 32, 7);
  blur(buf0, buf1, buf0, 64, 7, S + (size_t)8*NB*512);
  conv_noup(buf0, buf1, 64, 8, sT4);                    // last conv: scale by s_trgb4
  skipup(skipB, out, 32);                               // overwrite d_out (poison-safe)
  torgb(buf1, out, 64, 4, 1);                           // final skip add -> d_out
}

// Round 12
// 3540.400 us; speedup vs baseline: 1.4450x; 1.4450x over previous
//
#include <hip/hip_runtime.h>
#include <hip/hip_bf16.h>
#include <cstdio>
#include <math.h>

// ---------------------------------------------------------------------------
// StyleGANv2 generator forward. bf16 MFMA implicit-GEMM convolutions.
//   mod+demod conv == d[b,o] * conv(x * s'[b,i], w_shared); s' folded into the
//   producer epilogue so GEMM A-operand is a pure bf16 gather.
//   Up-conv: parity-decomposed (blockIdx.z = output parity class).
//   k_conv (R10 base + B-direct): 128x128 tile, tap-outer / unrolled-8-chunk
//   register-prefetch pipeline (R5/R9/R11 lesson: any other shape spills).
//   A staged in LDS (XOR-8 slot swizzle, 128B rows, 0 conflicts, b128-aligned).
//   B fragments read DIRECTLY from global (per-lane addr, L1/L2-resident
//   16KB/chunk working set) -> LDS traffic halved (96->48KB/chunk), LDS 16KB.
//   Blur: separable k1 x k1 (V then H pass).
// ---------------------------------------------------------------------------

static constexpr int NB = 32;
static constexpr float SQRT2F      = 1.41421356237309515f;
static constexpr float INV_SQRT512 = 0.04419417382415922f;   // 1/sqrt(512)
static constexpr float INV_SQRT4608= 0.014731391274719742f;  // 1/sqrt(512*9)

typedef __hip_bfloat16 bf16;
typedef __attribute__((ext_vector_type(8))) short bf16x8;
typedef __attribute__((ext_vector_type(4))) float f32x4;

__device__ __forceinline__ float lrelu_s2(float v){ return (v > 0.f ? v : 0.2f*v) * SQRT2F; }
__device__ __forceinline__ float bf_lo(unsigned u){ unsigned v = u << 16; return __builtin_bit_cast(float, v); }
__device__ __forceinline__ float bf_hi(unsigned u){ unsigned v = u & 0xffff0000u; return __builtin_bit_cast(float, v); }
__device__ __forceinline__ unsigned packbf2(float a, float b){
  bf16 ha = __float2bfloat16(a), hb = __float2bfloat16(b);
  unsigned short ra = __builtin_bit_cast(unsigned short, ha);
  unsigned short rb = __builtin_bit_cast(unsigned short, hb);
  return (unsigned)ra | ((unsigned)rb << 16);
}

// ---------------- mapping network: pixel_norm + 8x (512x512 lrelu) ----------
__global__ void k_mapping(const float* __restrict__ z, const float* __restrict__ mlp_w,
                          const float* __restrict__ mlp_b, float* __restrict__ wlat){
  __shared__ float xb[512], yb[512], red[256];
  int b = blockIdx.x, t = threadIdx.x;
  float z0 = z[b*512 + t], z1 = z[b*512 + t + 256];
  red[t] = z0*z0 + z1*z1;
  __syncthreads();
  for(int s = 128; s > 0; s >>= 1){ if(t < s) red[t] += red[t+s]; __syncthreads(); }
  float norm = sqrtf(red[0]) * INV_SQRT512;
  float inv = 1.f / (norm + 1e-6f);
  xb[t] = z0*inv; xb[t+256] = z1*inv;
  __syncthreads();
  for(int l = 0; l < 8; l++){
    const float* Wl = mlp_w + (size_t)l*512*512;
    const float* bl = mlp_b + l*512;
    for(int oo = 0; oo < 2; oo++){
      int o = t + oo*256;
      const float4* wr = (const float4*)(Wl + (size_t)o*512);
      float acc = 0.f;
      #pragma unroll 4
      for(int k = 0; k < 128; k++){
        float4 w4 = wr[k];
        acc += w4.x*xb[4*k] + w4.y*xb[4*k+1] + w4.z*xb[4*k+2] + w4.w*xb[4*k+3];
      }
      yb[o] = lrelu_s2(acc*INV_SQRT512 + bl[o]*0.01f);
    }
    __syncthreads();
    xb[t] = yb[t]; xb[t+256] = yb[t+256];
    __syncthreads();
  }
  wlat[b*512+t] = xb[t]; wlat[b*512+t+256] = xb[t+256];
}

// ---------------- styles: s' for 9 conv layers + 5 torgb layers -------------
__global__ void k_styles(const float* __restrict__ wlat,
                         const float* __restrict__ csw, const float* __restrict__ csb,
                         const float* __restrict__ tsw, const float* __restrict__ tsb,
                         float* __restrict__ s_conv, float* __restrict__ s_trgb){
  int gid = blockIdx.x*256 + threadIdx.x;        // 14*32*512 = 229376 exactly
  int l = gid >> 14;
  int b = (gid >> 9) & 31;
  int i = gid & 511;
  const float* row; float bias, wsc;
  if(l < 9){ row = csw + ((size_t)l*512 + i)*512; bias = csb[l*512+i]; wsc = INV_SQRT4608; }
  else     { int lt = l-9; row = tsw + ((size_t)lt*512 + i)*512; bias = tsb[lt*512+i]; wsc = INV_SQRT512; }
  const float4* r4 = (const float4*)row;
  const float4* w4 = (const float4*)(wlat + b*512);
  float acc = 0.f;
  #pragma unroll 4
  for(int k = 0; k < 128; k++){
    float4 a = w4[k], c = r4[k];
    acc += a.x*c.x + a.y*c.y + a.z*c.z + a.w*c.w;
  }
  float s = (acc*INV_SQRT512 + bias) * wsc;
  if(l < 9) s_conv[((size_t)l*32 + b)*512 + i] = s;
  else      s_trgb[((size_t)(l-9)*32 + b)*512 + i] = s;
}

// ---------------- fused: wsq[l,o,i] = sum w^2; wB[l][tap][o][i] = bf16(w) ----
__global__ void k_prep(const float* __restrict__ cw, float* __restrict__ wsq,
                       bf16* __restrict__ wB){
  int gid = blockIdx.x*256 + threadIdx.x;        // 9*512*512; (l,o,i)
  const float* p = cw + (size_t)gid*9;
  int l = gid >> 18;
  int oi = gid & 0x3ffff;                        // o*512 + i
  float v[9]; float a = 0.f;
  #pragma unroll
  for(int t = 0; t < 9; t++){ v[t] = p[t]; a += v[t]*v[t]; }
  wsq[gid] = a;
  #pragma unroll
  for(int tap = 0; tap < 9; tap++)
    wB[((size_t)(l*9 + tap) << 18) + oi] = __float2bfloat16(v[tap]);
}

// ---------------- demod d[l,b,o] ---------------------------------------------
__global__ void k_demod(const float* __restrict__ s_conv, const float* __restrict__ wsq,
                        float* __restrict__ d_conv){
  __shared__ float s2[512];
  int l = blockIdx.x/32, b = blockIdx.x%32, t = threadIdx.x;
  size_t base = ((size_t)l*32 + b)*512;
  float v0 = s_conv[base + t], v1 = s_conv[base + t + 256];
  s2[t] = v0*v0; s2[t+256] = v1*v1;
  __syncthreads();
  for(int oo = 0; oo < 2; oo++){
    int o = t + oo*256;
    const float4* wr = (const float4*)(wsq + ((size_t)l*512 + o)*512);
    float acc = 0.f;
    #pragma unroll 4
    for(int k = 0; k < 128; k++){
      float4 w = wr[k];
      acc += w.x*s2[4*k] + w.y*s2[4*k+1] + w.z*s2[4*k+2] + w.w*s2[4*k+3];
    }
    d_conv[base + o] = rsqrtf(acc + 1e-8f);
  }
}

// ---------------- torgb compensation ratio ----------------------------------
__global__ void k_ratio(const float* __restrict__ s_conv, const float* __restrict__ s_trgb,
                        float* __restrict__ rat){
  int gid = blockIdx.x*256 + threadIdx.x;        // 5*32*512 = 81920
  int lt = gid >> 14;
  if(lt >= 4){ rat[gid] = 1.0f; return; }
  int b = (gid >> 9) & 31;
  int i = gid & 511;
  int cl = 1 + 2*lt;                             // consuming conv layer
  float st = s_trgb[((size_t)lt*32 + b)*512 + i];
  float sc = s_conv[((size_t)cl*32 + b)*512 + i];
  rat[gid] = (sc != 0.f) ? st/sc : 0.f;
}

// ---------------- const input -> act0 (B,4,4,512) pre-scaled by s_conv[0] ----
__global__ void k_init(const float* __restrict__ ci, const float* __restrict__ s_conv,
                       bf16* __restrict__ act){
  int gid = blockIdx.x*256 + threadIdx.x;        // 32*16*512 = 262144
  int c = gid & 511; int px = (gid >> 9) & 15; int b = gid >> 13;
  act[gid] = __float2bfloat16(ci[c*16 + px] * s_conv[b*512 + c]);
}

// ---------------- main conv: MFMA implicit GEMM (A in LDS, B direct) ---------
template<bool UP>
__global__ __launch_bounds__(256, 2)
void k_conv(const bf16* __restrict__ act, const bf16* __restrict__ wL,
            const float* __restrict__ dL, const float* __restrict__ noise,
            const float* __restrict__ nw_ptr, const float* __restrict__ ab,
            const float* __restrict__ sN, bf16* __restrict__ outp,
            int Hin, int Mblocks){
  // n-inner 1D grid + bijective XCD swizzle (gridDim.x is a multiple of 8)
  const int q8 = gridDim.x >> 3;
  const int swz = (blockIdx.x & 7)*q8 + (blockIdx.x >> 3);
  const int nb = swz & 3, mb = swz >> 2;
  if(mb >= Mblocks) return;
  const int mbase = mb*128, nbase = nb*128;

  int py = 0, px = 0;
  int OHy, OHx;
  if(UP){
    int cls = blockIdx.z; py = cls >> 1; px = cls & 1;
    OHy = Hin + 1 - py; OHx = Hin + 1 - px;      // class output dims
  } else {
    OHy = Hin; OHx = Hin;
  }
  const int pixN = OHy*OHx;
  const int Mtot = NB*pixN;
  if(mbase >= Mtot) return;

  // LDS (A only): 128 rows x 64 shorts (128B). 16B slot s stored at s^(row&7).
  __shared__ short As[128*64];
  const int t = threadIdx.x;
  const int row  = t >> 1;                       // staging row 0..127
  const int half = t & 1;                        // 64B half of the row
  const int r7   = row & 7;

  int m = mbase + row;
  const bool mval = (m < Mtot);
  int mm = mval ? m : 0;
  const int gb = mm / pixN; int rem = mm % pixN;
  const int gY = rem / OHx, gX = rem % OHx;

  // wave fragment geometry (4 waves, 2x2 over 128x128)
  const int wid = t >> 6;
  const int mrow0 = (wid >> 1)*64;
  const int ncol0 = (wid & 1)*64;
  const int lr = t & 15;
  const int ks = (t & 63) >> 4;
  const int lr7 = lr & 7;
  const int sw0 = (ks ^ lr7)*8;
  const int sw1 = ((4 + ks) ^ lr7)*8;

  int wsl[4];
  #pragma unroll
  for(int j = 0; j < 4; j++) wsl[j] = ((half*4 + j) ^ r7)*8;

  f32x4 acc[4][4];
  #pragma unroll
  for(int i = 0; i < 4; i++)
    #pragma unroll
    for(int j = 0; j < 4; j++) acc[i][j] = (f32x4){0.f,0.f,0.f,0.f};

  // tap lists (parity-valid subset for UP; all 9 otherwise)
  int dyl[3], dxl[3], ndy, ndx;
  if(UP){
    if(py == 0){ dyl[0]=0; dyl[1]=2; ndy=2; } else { dyl[0]=1; ndy=1; }
    if(px == 0){ dxl[0]=0; dxl[1]=2; ndx=2; } else { dxl[0]=1; ndx=1; }
  } else {
    dyl[0]=0; dyl[1]=1; dyl[2]=2; ndy=3;
    dxl[0]=0; dxl[1]=1; dxl[2]=2; ndx=3;
  }
  const int TT = ndy*ndx;

  // per-lane B fragment base: row (nbase+ncol0+lr), k-slot ks (8 bf16)
  const bf16* bRow = wL + ((size_t)(nbase + ncol0 + lr) << 9) + ks*8;

  for(int tt = 0; tt < TT; tt++){
    const int dy = dyl[tt/ndx], dx = dxl[tt%ndx];
    const int tap = dy*3 + dx;
    bool aok = false; const bf16* aptr = act;
    {
      int yy, xx;
      if(UP){ yy = gY - ((dy - py) >> 1); xx = gX - ((dx - px) >> 1); }
      else  { yy = gY + dy - 1;           xx = gX + dx - 1; }
      if(mval && (unsigned)yy < (unsigned)Hin && (unsigned)xx < (unsigned)Hin){
        aok = true;
        aptr = act + ((size_t)((gb*Hin + yy)*Hin + xx) << 9) + half*32;
      }
    }
    const bf16* bTap = bRow + ((size_t)tap << 18);

    // prefetch A chunk 0 (4 x 16B)
    uint4 pa[4];
    #pragma unroll
    for(int j = 0; j < 4; j++)
      pa[j] = aok ? *(const uint4*)(aptr + j*8) : make_uint4(0u,0u,0u,0u);

    #pragma unroll
    for(int c = 0; c < 8; c++){
      asm volatile("" ::: "memory");
      __builtin_amdgcn_s_barrier();              // prev iter's LDS reads done
      #pragma unroll
      for(int j = 0; j < 4; j++)
        *(uint4*)&As[row*64 + wsl[j]] = pa[j];
      uint4 na[4];
      if(c < 7){
        const int koff = (c+1)*64;
        #pragma unroll
        for(int j = 0; j < 4; j++)
          na[j] = aok ? *(const uint4*)(aptr + koff + j*8) : make_uint4(0u,0u,0u,0u);
      }
      asm volatile("s_waitcnt lgkmcnt(0)" ::: "memory");  // my LDS writes done
      __builtin_amdgcn_s_barrier();              // tile ready; prefetch in flight
      // B fragments direct from global (L1/L2-resident), both halves
      bf16x8 bf0[4], bf1[4];
      #pragma unroll
      for(int f = 0; f < 4; f++){
        const bf16* bq = bTap + (size_t)f*8192 + c*64;
        bf0[f] = *(const bf16x8*)(bq);
        bf1[f] = *(const bf16x8*)(bq + 32);
      }
      #pragma unroll
      for(int h = 0; h < 2; h++){
        const int swr = h ? sw1 : sw0;
        bf16x8 af[4];
        #pragma unroll
        for(int f = 0; f < 4; f++)
          af[f] = *(const bf16x8*)&As[(mrow0 + f*16 + lr)*64 + swr];
        #pragma unroll
        for(int mf = 0; mf < 4; mf++)
          #pragma unroll
          for(int nf = 0; nf < 4; nf++)
            acc[mf][nf] = __builtin_amdgcn_mfma_f32_16x16x32_bf16(
                af[mf], h ? bf1[nf] : bf0[nf], acc[mf][nf], 0, 0, 0);
      }
      if(c < 7){
        #pragma unroll
        for(int j = 0; j < 4; j++) pa[j] = na[j];
      }
    }
  }

  // epilogue: C/D frag mapping col=lane&15, row=(lane>>4)*4+reg  [m89-verified]
  const float nwv = UP ? 0.f : *nw_ptr;
  const int U = 2*Hin + 1;
  #pragma unroll
  for(int mf = 0; mf < 4; mf++){
    #pragma unroll
    for(int r = 0; r < 4; r++){
      int me = mbase + mrow0 + mf*16 + ks*4 + r;
      if(me >= Mtot) continue;
      int b = me / pixN; int rem2 = me % pixN; int y = rem2 / OHx, x = rem2 % OHx;
      const float* drow = dL + b*512;
      bf16* orow;
      float nz = 0.f; const float* srow = nullptr;
      if(UP){
        orow = outp + (((size_t)((b*U + 2*y + py))*U + (2*x + px)) << 9);
      } else {
        nz = nwv * noise[(b*OHy + y)*OHx + x];
        srow = sN + b*512;
        orow = outp + ((size_t)me << 9);
      }
      #pragma unroll
      for(int nf = 0; nf < 4; nf++){
        int n = nbase + ncol0 + nf*16 + lr;
        float val = acc[mf][nf][r] * drow[n];
        if(!UP) val = lrelu_s2(val + nz + ab[n]) * srow[n];
        orow[n] = __float2bfloat16(val);
      }
    }
  }
}

// ---------------- separable blur: V pass (u -> tmp) --------------------------
__global__ void k_blurV(const bf16* __restrict__ u, bf16* __restrict__ tmp, int O){
  const int U = O + 1;
  size_t gid = (size_t)blockIdx.x*256 + threadIdx.x;
  size_t total = (size_t)NB*O*U*128;
  if(gid >= total) return;
  int c4 = gid & 127;
  size_t pix = gid >> 7;                         // (b*O + Y)*U + X
  int X = pix % U; int Y = (pix/U) % O; int b = pix/((size_t)O*U);
  const float k1[4] = {0.25f, 0.75f, 0.75f, 0.25f};
  float4 a = make_float4(0.f,0.f,0.f,0.f);
  #pragma unroll
  for(int ky = 0; ky < 4; ky++){
    int yy = Y + ky - 1; if(yy < 0 || yy >= U) continue;
    float w = k1[ky];
    uint2 u2 = *(const uint2*)(u + (((size_t)(b*U + yy)*U + X) << 9) + c4*4);
    a.x += w*bf_lo(u2.x); a.y += w*bf_hi(u2.x);
    a.z += w*bf_lo(u2.y); a.w += w*bf_hi(u2.y);
  }
  uint2 pk;
  pk.x = packbf2(a.x, a.y); pk.y = packbf2(a.z, a.w);
  *(uint2*)(tmp + (pix << 9) + c4*4) = pk;
}

// ------- separable blur: H pass + noise + bias + lrelu + next-scale ----------
__global__ void k_blurH(const bf16* __restrict__ tmp, const float* __restrict__ noise,
                        const float* __restrict__ nw_ptr, const float* __restrict__ ab,
                        const float* __restrict__ sN, bf16* __restrict__ act, int O){
  const int U = O + 1;
  size_t gid = (size_t)blockIdx.x*256 + threadIdx.x;
  size_t total = (size_t)NB*O*O*128;
  if(gid >= total) return;
  int c4 = gid & 127;
  size_t pix = gid >> 7;                         // (b*O + Y)*O + X
  int X = pix % O; int Y = (pix/O) % O; int b = pix/((size_t)O*O);
  const float k1[4] = {0.25f, 0.75f, 0.75f, 0.25f};
  float4 a = make_float4(0.f,0.f,0.f,0.f);
  #pragma unroll
  for(int kx = 0; kx < 4; kx++){
    int xx = X + kx - 1; if(xx < 0 || xx >= U) continue;
    float w = k1[kx];
    uint2 u2 = *(const uint2*)(tmp + (((size_t)(b*O + Y)*U + xx) << 9) + c4*4);
    a.x += w*bf_lo(u2.x); a.y += w*bf_hi(u2.x);
    a.z += w*bf_lo(u2.y); a.w += w*bf_hi(u2.y);
  }
  float nz = (*nw_ptr) * noise[(b*O + Y)*O + X];
  const float* abp4 = ab + c4*4;
  float4 s4 = *(const float4*)(sN + b*512 + c4*4);
  uint2 pk;
  pk.x = packbf2(lrelu_s2(a.x + nz + abp4[0])*s4.x, lrelu_s2(a.y + nz + abp4[1])*s4.y);
  pk.y = packbf2(lrelu_s2(a.z + nz + abp4[2])*s4.z, lrelu_s2(a.w + nz + abp4[3])*s4.w);
  *(uint2*)(act + (pix << 9) + c4*4) = pk;
}

// ---------------- toRGB (1x1 mod conv, no demod) -> NCHW skip ----------------
__global__ void k_torgb(const bf16* __restrict__ act, const float* __restrict__ tw,
                        const float* __restrict__ ratL, const float* __restrict__ tbias,
                        float* __restrict__ dst, int H, int lt, int addflag){
  int wid = threadIdx.x >> 6, lane = threadIdx.x & 63;
  int pix = blockIdx.x*4 + wid;
  int npix = NB*H*H;
  if(pix >= npix) return;
  int b = pix/(H*H);
  const bf16* ap = act + ((size_t)pix << 9);
  const float* rp = ratL + (size_t)b*512;
  const float* w0 = tw + ((size_t)lt*3 + 0)*512;
  const float* w1 = tw + ((size_t)lt*3 + 1)*512;
  const float* w2 = tw + ((size_t)lt*3 + 2)*512;
  float a0 = 0.f, a1 = 0.f, a2 = 0.f;
  #pragma unroll
  for(int j = 0; j < 8; j++){
    int i = lane + j*64;
    float xs = __bfloat162float(ap[i])*rp[i];
    a0 += xs*w0[i]; a1 += xs*w1[i]; a2 += xs*w2[i];
  }
  for(int off = 32; off > 0; off >>= 1){
    a0 += __shfl_xor(a0, off);
    a1 += __shfl_xor(a1, off);
    a2 += __shfl_xor(a2, off);
  }
  if(lane == 0){
    int rem = pix % (H*H);
    size_t o0 = ((size_t)(b*3 + 0)*H*H) + rem;
    size_t o1 = ((size_t)(b*3 + 1)*H*H) + rem;
    size_t o2 = ((size_t)(b*3 + 2)*H*H) + rem;
    float b0 = tbias[lt*3+0], b1 = tbias[lt*3+1], b2 = tbias[lt*3+2];
    if(addflag){ dst[o0] += a0 + b0; dst[o1] += a1 + b1; dst[o2] += a2 + b2; }
    else       { dst[o0]  = a0 + b0; dst[o1]  = a1 + b1; dst[o2]  = a2 + b2; }
  }
}

// ---------------- skip upsample 2x (NCHW, 3ch) -------------------------------
__global__ void k_skipup(const float* __restrict__ sin, float* __restrict__ sout, int h){
  const int O = 2*h;
  int gid = blockIdx.x*256 + threadIdx.x;
  int total = NB*3*O*O;
  if(gid >= total) return;
  int X = gid % O; int Y = (gid/O) % O; int c = (gid/(O*O)) % 3; int b = gid/(3*O*O);
  const float k1[4] = {1.f, 3.f, 3.f, 1.f};
  float acc = 0.f;
  for(int ky = (Y & 1); ky < 4; ky += 2){
    int ty = Y + ky - 2;
    if(ty < 0) continue;
    int y = ty >> 1; if(y >= h) continue;
    for(int kx = (X & 1); kx < 4; kx += 2){
      int tx = X + kx - 2;
      if(tx < 0) continue;
      int x = tx >> 1; if(x >= h) continue;
      acc += k1[ky]*k1[kx]*(1.f/16.f) * sin[((size_t)(b*3 + c)*h + y)*h + x];
    }
  }
  sout[gid] = acc;
}

// ---------------------------------------------------------------------------
extern "C" void kernel_launch(void* const* d_in, const int* in_sizes, int n_in,
                              void* d_out, int out_size, void* d_ws, size_t ws_size,
                              hipStream_t stream){
  const float* z     = (const float*)d_in[0];
  const float* mlp_w = (const float*)d_in[1];
  const float* mlp_b = (const float*)d_in[2];
  const float* cinp  = (const float*)d_in[3];
  const float* conv_w= (const float*)d_in[4];
  const float* csw   = (const float*)d_in[5];
  const float* csb   = (const float*)d_in[6];
  const float* nwp   = (const float*)d_in[7];
  const float* abp   = (const float*)d_in[8];
  const float* tw    = (const float*)d_in[9];
  const float* tsw   = (const float*)d_in[10];
  const float* tsb   = (const float*)d_in[11];
  const float* tb    = (const float*)d_in[12];
  const float* noise[9];
  for(int i = 0; i < 9; i++) noise[i] = (const float*)d_in[13 + i];

  // workspace layout (bytes)
  const size_t UMAX = (size_t)32*65*65*512;       // 69,206,016 elems
  char* base = (char*)d_ws;
  size_t off = 0;
  bf16* buf0 = (bf16*)(base + off); off += UMAX*2;                 // 138,412,032
  bf16* buf1 = (bf16*)(base + off); off += UMAX*2;                 // 138,412,032
  bf16* wB   = (bf16*)(base + off); off += (size_t)9*9*512*512*2;  //  42,467,328
  float* wsq = (float*)(base + off); off += (size_t)9*512*512*4;   //   9,437,184
  float* wlat= (float*)(base + off); off += (size_t)32*512*4;
  float* sconv=(float*)(base + off); off += (size_t)9*32*512*4;
  float* dconv=(float*)(base + off); off += (size_t)9*32*512*4;
  float* strgb=(float*)(base + off); off += (size_t)5*32*512*4;
  float* rat  =(float*)(base + off); off += (size_t)5*32*512*4;
  float* skipA=(float*)(base + off); off += (size_t)32*3*64*64*4;
  float* skipB=(float*)(base + off); off += (size_t)32*3*64*64*4;
  if(ws_size < off){
    fprintf(stderr, "kernel_launch: ws too small (%zu < %zu)\n", ws_size, off);
    return;
  }
  float* out = (float*)d_out;

  // prep
  k_mapping<<<32, 256, 0, stream>>>(z, mlp_w, mlp_b, wlat);
  k_styles <<<896, 256, 0, stream>>>(wlat, csw, csb, tsw, tsb, sconv, strgb);
  k_prep   <<<9216, 256, 0, stream>>>(conv_w, wsq, wB);
  k_demod  <<<288, 256, 0, stream>>>(sconv, wsq, dconv);
  k_ratio  <<<320, 256, 0, stream>>>(sconv, strgb, rat);
  k_init   <<<1024, 256, 0, stream>>>(cinp, sconv, buf0);

  auto conv_noup = [&](const bf16* in, bf16* o, int H, int layer, const float* sN){
    int M = 32*H*H; int Mb = (M + 127)/128;
    int Gx = ((Mb*4 + 7)/8)*8;
    k_conv<false><<<dim3(Gx,1,1), 256, 0, stream>>>(in, wB + ((size_t)layer*9 << 18),
        dconv + (size_t)layer*NB*512, noise[layer], nwp + layer, abp + layer*512, sN, o, H, Mb);
  };
  auto conv_up = [&](const bf16* in, bf16* o, int Hin, int layer){
    int Mmax = 32*(Hin+1)*(Hin+1); int Mb = (Mmax + 127)/128;
    int Gx = ((Mb*4 + 7)/8)*8;
    k_conv<true><<<dim3(Gx,1,4), 256, 0, stream>>>(in, wB + ((size_t)layer*9 << 18),
        dconv + (size_t)layer*NB*512, nullptr, nullptr, nullptr, nullptr, o, Hin, Mb);
  };
  auto blur = [&](const bf16* u, bf16* tmp, bf16* o, int O, int layer, const float* sN){
    size_t totV = (size_t)32*O*(O+1)*128;
    size_t totH = (size_t)32*O*O*128;
    k_blurV<<<(unsigned)((totV + 255)/256), 256, 0, stream>>>(u, tmp, O);
    k_blurH<<<(unsigned)((totH + 255)/256), 256, 0, stream>>>(tmp, noise[layer], nwp + layer,
        abp + layer*512, sN, o, O);
  };
  auto torgb = [&](const bf16* act, float* dst, int H, int lt, int add){
    int npix = 32*H*H;
    k_torgb<<<(npix + 3)/4, 256, 0, stream>>>(act, tw, rat + (size_t)lt*NB*512, tb, dst, H, lt, add);
  };
  auto skipup = [&](const float* sin, float* sout, int h){
    int total = 32*3*(2*h)*(2*h);
    k_skipup<<<(total + 255)/256, 256, 0, stream>>>(sin, sout, h);
  };

  const float* S = sconv;   // s rows per layer: S + layer*NB*512
  const float* sT4 = strgb + (size_t)4*NB*512;

  // layer 0 @4   (buf0 = act0; output scaled by s1)
  conv_noup(buf0, buf1, 4, 0, S + (size_t)1*NB*512);   // buf0 -> buf1
  torgb(buf1, skipA, 4, 0, 0);

  // r=0: 4->8
  conv_up(buf1, buf0, 4, 1);                            // buf1 -> buf0 (u)
  blur(buf0, buf1, buf0, 8, 1, S + (size_t)2*NB*512);   // V: 0->1, H: 1->0 (act8)
  conv_noup(buf0, buf1, 8, 2, S + (size_t)3*NB*512);    // buf0 -> buf1
  skipup(skipA, skipB, 4);
  torgb(buf1, skipB, 8, 1, 1);

  // r=1: 8->16
  conv_up(buf1, buf0, 8, 3);
  blur(buf0, buf1, buf0, 16, 3, S + (size_t)4*NB*512);
  conv_noup(buf0, buf1, 16, 4, S + (size_t)5*NB*512);
  skipup(skipB, skipA, 8);
  torgb(buf1, skipA, 16, 2, 1);

  // r=2: 16->32
  conv_up(buf1, buf0, 16, 5);
  blur(buf0, buf1, buf0, 32, 5, S + (size_t)6*NB*512);
  conv_noup(buf0, buf1, 32, 6, S + (size_t)7*NB*512);
  skipup(skipA, skipB, 16);
  torgb(buf1, skipB, 32, 3, 1);

  // r=3: 32->64
  conv_up(buf1, buf0, 32, 7);
  blur(buf0, buf1, buf0, 64, 7, S + (size_t)8*NB*512);
  conv_noup(buf0, buf1, 64, 8, sT4);                    // last conv: scale by s_trgb4
  skipup(skipB, out, 32);                               // overwrite d_out (poison-safe)
  torgb(buf1, out, 64, 4, 1);                           // final skip add -> d_out
}

// Round 13
// 2165.476 us; speedup vs baseline: 2.3624x; 1.6349x over previous
//
#include <hip/hip_runtime.h>
#include <hip/hip_bf16.h>
#include <cstdio>
#include <math.h>

// ---------------------------------------------------------------------------
// StyleGANv2 generator forward. bf16 MFMA implicit-GEMM convolutions.
//   mod+demod conv == d[b,o] * conv(x * s'[b,i], w_shared); s' folded into the
//   producer epilogue so GEMM A-operand is a pure bf16 gather.
//   Up-conv: parity-decomposed (blockIdx.z = output parity class).
//   k_conv  (R10): 128x128 tile, 4 waves 2x2 (64x64), tap-outer / unrolled-8-
//   chunk register-prefetch, raw s_barrier x2/chunk, XOR-8 LDS slot swizzle.
//   k_conv2 (NEW): 256x256 tile, 512 thr, 8 waves 2Mx4N (wave 128x64, acc 8x4)
//   — halves LDS bytes/FLOP (0.047->0.031); used for big non-up layers only.
//   R5/R9/R11: runtime/unrolled cross-tap pipelines spill — keep tap-outer.
//   R12: B-direct-from-global is L1-throughput-bound — both operands in LDS.
//   Blur: separable k1 x k1 (V then H pass).
// ---------------------------------------------------------------------------

static constexpr int NB = 32;
static constexpr float SQRT2F      = 1.41421356237309515f;
static constexpr float INV_SQRT512 = 0.04419417382415922f;   // 1/sqrt(512)
static constexpr float INV_SQRT4608= 0.014731391274719742f;  // 1/sqrt(512*9)

typedef __hip_bfloat16 bf16;
typedef __attribute__((ext_vector_type(8))) short bf16x8;
typedef __attribute__((ext_vector_type(4))) float f32x4;

__device__ __forceinline__ float lrelu_s2(float v){ return (v > 0.f ? v : 0.2f*v) * SQRT2F; }
__device__ __forceinline__ float bf_lo(unsigned u){ unsigned v = u << 16; return __builtin_bit_cast(float, v); }
__device__ __forceinline__ float bf_hi(unsigned u){ unsigned v = u & 0xffff0000u; return __builtin_bit_cast(float, v); }
__device__ __forceinline__ unsigned packbf2(float a, float b){
  bf16 ha = __float2bfloat16(a), hb = __float2bfloat16(b);
  unsigned short ra = __builtin_bit_cast(unsigned short, ha);
  unsigned short rb = __builtin_bit_cast(unsigned short, hb);
  return (unsigned)ra | ((unsigned)rb << 16);
}

// ---------------- mapping network: pixel_norm + 8x (512x512 lrelu) ----------
__global__ void k_mapping(const float* __restrict__ z, const float* __restrict__ mlp_w,
                          const float* __restrict__ mlp_b, float* __restrict__ wlat){
  __shared__ float xb[512], yb[512], red[256];
  int b = blockIdx.x, t = threadIdx.x;
  float z0 = z[b*512 + t], z1 = z[b*512 + t + 256];
  red[t] = z0*z0 + z1*z1;
  __syncthreads();
  for(int s = 128; s > 0; s >>= 1){ if(t < s) red[t] += red[t+s]; __syncthreads(); }
  float norm = sqrtf(red[0]) * INV_SQRT512;
  float inv = 1.f / (norm + 1e-6f);
  xb[t] = z0*inv; xb[t+256] = z1*inv;
  __syncthreads();
  for(int l = 0; l < 8; l++){
    const float* Wl = mlp_w + (size_t)l*512*512;
    const float* bl = mlp_b + l*512;
    for(int oo = 0; oo < 2; oo++){
      int o = t + oo*256;
      const float4* wr = (const float4*)(Wl + (size_t)o*512);
      float acc = 0.f;
      #pragma unroll 4
      for(int k = 0; k < 128; k++){
        float4 w4 = wr[k];
        acc += w4.x*xb[4*k] + w4.y*xb[4*k+1] + w4.z*xb[4*k+2] + w4.w*xb[4*k+3];
      }
      yb[o] = lrelu_s2(acc*INV_SQRT512 + bl[o]*0.01f);
    }
    __syncthreads();
    xb[t] = yb[t]; xb[t+256] = yb[t+256];
    __syncthreads();
  }
  wlat[b*512+t] = xb[t]; wlat[b*512+t+256] = xb[t+256];
}

// ---------------- styles: s' for 9 conv layers + 5 torgb layers -------------
__global__ void k_styles(const float* __restrict__ wlat,
                         const float* __restrict__ csw, const float* __restrict__ csb,
                         const float* __restrict__ tsw, const float* __restrict__ tsb,
                         float* __restrict__ s_conv, float* __restrict__ s_trgb){
  int gid = blockIdx.x*256 + threadIdx.x;        // 14*32*512 = 229376 exactly
  int l = gid >> 14;
  int b = (gid >> 9) & 31;
  int i = gid & 511;
  const float* row; float bias, wsc;
  if(l < 9){ row = csw + ((size_t)l*512 + i)*512; bias = csb[l*512+i]; wsc = INV_SQRT4608; }
  else     { int lt = l-9; row = tsw + ((size_t)lt*512 + i)*512; bias = tsb[lt*512+i]; wsc = INV_SQRT512; }
  const float4* r4 = (const float4*)row;
  const float4* w4 = (const float4*)(wlat + b*512);
  float acc = 0.f;
  #pragma unroll 4
  for(int k = 0; k < 128; k++){
    float4 a = w4[k], c = r4[k];
    acc += a.x*c.x + a.y*c.y + a.z*c.z + a.w*c.w;
  }
  float s = (acc*INV_SQRT512 + bias) * wsc;
  if(l < 9) s_conv[((size_t)l*32 + b)*512 + i] = s;
  else      s_trgb[((size_t)(l-9)*32 + b)*512 + i] = s;
}

// ---------------- fused: wsq[l,o,i] = sum w^2; wB[l][tap][o][i] = bf16(w) ----
__global__ void k_prep(const float* __restrict__ cw, float* __restrict__ wsq,
                       bf16* __restrict__ wB){
  int gid = blockIdx.x*256 + threadIdx.x;        // 9*512*512; (l,o,i)
  const float* p = cw + (size_t)gid*9;
  int l = gid >> 18;
  int oi = gid & 0x3ffff;                        // o*512 + i
  float v[9]; float a = 0.f;
  #pragma unroll
  for(int t = 0; t < 9; t++){ v[t] = p[t]; a += v[t]*v[t]; }
  wsq[gid] = a;
  #pragma unroll
  for(int tap = 0; tap < 9; tap++)
    wB[((size_t)(l*9 + tap) << 18) + oi] = __float2bfloat16(v[tap]);
}

// ---------------- demod d[l,b,o] ---------------------------------------------
__global__ void k_demod(const float* __restrict__ s_conv, const float* __restrict__ wsq,
                        float* __restrict__ d_conv){
  __shared__ float s2[512];
  int l = blockIdx.x/32, b = blockIdx.x%32, t = threadIdx.x;
  size_t base = ((size_t)l*32 + b)*512;
  float v0 = s_conv[base + t], v1 = s_conv[base + t + 256];
  s2[t] = v0*v0; s2[t+256] = v1*v1;
  __syncthreads();
  for(int oo = 0; oo < 2; oo++){
    int o = t + oo*256;
    const float4* wr = (const float4*)(wsq + ((size_t)l*512 + o)*512);
    float acc = 0.f;
    #pragma unroll 4
    for(int k = 0; k < 128; k++){
      float4 w = wr[k];
      acc += w.x*s2[4*k] + w.y*s2[4*k+1] + w.z*s2[4*k+2] + w.w*s2[4*k+3];
    }
    d_conv[base + o] = rsqrtf(acc + 1e-8f);
  }
}

// ---------------- torgb compensation ratio ----------------------------------
__global__ void k_ratio(const float* __restrict__ s_conv, const float* __restrict__ s_trgb,
                        float* __restrict__ rat){
  int gid = blockIdx.x*256 + threadIdx.x;        // 5*32*512 = 81920
  int lt = gid >> 14;
  if(lt >= 4){ rat[gid] = 1.0f; return; }
  int b = (gid >> 9) & 31;
  int i = gid & 511;
  int cl = 1 + 2*lt;                             // consuming conv layer
  float st = s_trgb[((size_t)lt*32 + b)*512 + i];
  float sc = s_conv[((size_t)cl*32 + b)*512 + i];
  rat[gid] = (sc != 0.f) ? st/sc : 0.f;
}

// ---------------- const input -> act0 (B,4,4,512) pre-scaled by s_conv[0] ----
__global__ void k_init(const float* __restrict__ ci, const float* __restrict__ s_conv,
                       bf16* __restrict__ act){
  int gid = blockIdx.x*256 + threadIdx.x;        // 32*16*512 = 262144
  int c = gid & 511; int px = (gid >> 9) & 15; int b = gid >> 13;
  act[gid] = __float2bfloat16(ci[c*16 + px] * s_conv[b*512 + c]);
}

// ---------------- main conv 128x128 (R10 structure) --------------------------
template<bool UP>
__global__ __launch_bounds__(256, 2)
void k_conv(const bf16* __restrict__ act, const bf16* __restrict__ wL,
            const float* __restrict__ dL, const float* __restrict__ noise,
            const float* __restrict__ nw_ptr, const float* __restrict__ ab,
            const float* __restrict__ sN, bf16* __restrict__ outp,
            int Hin, int Mblocks){
  const int q8 = gridDim.x >> 3;
  const int swz = (blockIdx.x & 7)*q8 + (blockIdx.x >> 3);
  const int nb = swz & 3, mb = swz >> 2;
  if(mb >= Mblocks) return;
  const int mbase = mb*128, nbase = nb*128;

  int py = 0, px = 0;
  int OHy, OHx;
  if(UP){
    int cls = blockIdx.z; py = cls >> 1; px = cls & 1;
    OHy = Hin + 1 - py; OHx = Hin + 1 - px;
  } else {
    OHy = Hin; OHx = Hin;
  }
  const int pixN = OHy*OHx;
  const int Mtot = NB*pixN;
  if(mbase >= Mtot) return;

  __shared__ short As[128*64];
  __shared__ short Bs[128*64];
  const int t = threadIdx.x;
  const int row  = t >> 1;
  const int half = t & 1;
  const int r7   = row & 7;

  int m = mbase + row;
  const bool mval = (m < Mtot);
  int mm = mval ? m : 0;
  const int gb = mm / pixN; int rem = mm % pixN;
  const int gY = rem / OHx, gX = rem % OHx;

  const int wid = t >> 6;
  const int mrow0 = (wid >> 1)*64;
  const int ncol0 = (wid & 1)*64;
  const int lr = t & 15;
  const int ks = (t & 63) >> 4;
  const int lr7 = lr & 7;
  const int sw0 = (ks ^ lr7)*8;
  const int sw1 = ((4 + ks) ^ lr7)*8;

  int wsl[4];
  #pragma unroll
  for(int j = 0; j < 4; j++) wsl[j] = ((half*4 + j) ^ r7)*8;

  f32x4 acc[4][4];
  #pragma unroll
  for(int i = 0; i < 4; i++)
    #pragma unroll
    for(int j = 0; j < 4; j++) acc[i][j] = (f32x4){0.f,0.f,0.f,0.f};

  int dyl[3], dxl[3], ndy, ndx;
  if(UP){
    if(py == 0){ dyl[0]=0; dyl[1]=2; ndy=2; } else { dyl[0]=1; ndy=1; }
    if(px == 0){ dxl[0]=0; dxl[1]=2; ndx=2; } else { dxl[0]=1; ndx=1; }
  } else {
    dyl[0]=0; dyl[1]=1; dyl[2]=2; ndy=3;
    dxl[0]=0; dxl[1]=1; dxl[2]=2; ndx=3;
  }
  const int TT = ndy*ndx;

  const bf16* browB = wL + ((size_t)(nbase + row) << 9) + half*32;

  for(int tt = 0; tt < TT; tt++){
    const int dy = dyl[tt/ndx], dx = dxl[tt%ndx];
    const int tap = dy*3 + dx;
    bool aok = false; const bf16* aptr = act;
    {
      int yy, xx;
      if(UP){ yy = gY - ((dy - py) >> 1); xx = gX - ((dx - px) >> 1); }
      else  { yy = gY + dy - 1;           xx = gX + dx - 1; }
      if(mval && (unsigned)yy < (unsigned)Hin && (unsigned)xx < (unsigned)Hin){
        aok = true;
        aptr = act + ((size_t)((gb*Hin + yy)*Hin + xx) << 9) + half*32;
      }
    }
    const bf16* bptr = browB + ((size_t)tap << 18);

    uint4 pa[4], pb[4];
    #pragma unroll
    for(int j = 0; j < 4; j++){
      pa[j] = aok ? *(const uint4*)(aptr + j*8) : make_uint4(0u,0u,0u,0u);
      pb[j] = *(const uint4*)(bptr + j*8);
    }

    #pragma unroll
    for(int c = 0; c < 8; c++){
      asm volatile("" ::: "memory");
      __builtin_amdgcn_s_barrier();
      #pragma unroll
      for(int j = 0; j < 4; j++){
        *(uint4*)&As[row*64 + wsl[j]] = pa[j];
        *(uint4*)&Bs[row*64 + wsl[j]] = pb[j];
      }
      uint4 na[4], nb4[4];
      if(c < 7){
        const int koff = (c+1)*64;
        #pragma unroll
        for(int j = 0; j < 4; j++){
          na[j]  = aok ? *(const uint4*)(aptr + koff + j*8) : make_uint4(0u,0u,0u,0u);
          nb4[j] = *(const uint4*)(bptr + koff + j*8);
        }
      }
      asm volatile("s_waitcnt lgkmcnt(0)" ::: "memory");
      __builtin_amdgcn_s_barrier();
      #pragma unroll
      for(int h = 0; h < 2; h++){
        const int swr = h ? sw1 : sw0;
        bf16x8 af[4], bfr[4];
        #pragma unroll
        for(int f = 0; f < 4; f++){
          af[f]  = *(const bf16x8*)&As[(mrow0 + f*16 + lr)*64 + swr];
          bfr[f] = *(const bf16x8*)&Bs[(ncol0 + f*16 + lr)*64 + swr];
        }
        #pragma unroll
        for(int mf = 0; mf < 4; mf++)
          #pragma unroll
          for(int nf = 0; nf < 4; nf++)
            acc[mf][nf] = __builtin_amdgcn_mfma_f32_16x16x32_bf16(af[mf], bfr[nf], acc[mf][nf], 0, 0, 0);
      }
      if(c < 7){
        #pragma unroll
        for(int j = 0; j < 4; j++){ pa[j] = na[j]; pb[j] = nb4[j]; }
      }
    }
  }

  const float nwv = UP ? 0.f : *nw_ptr;
  const int U = 2*Hin + 1;
  #pragma unroll
  for(int mf = 0; mf < 4; mf++){
    #pragma unroll
    for(int r = 0; r < 4; r++){
      int me = mbase + mrow0 + mf*16 + ks*4 + r;
      if(me >= Mtot) continue;
      int b = me / pixN; int rem2 = me % pixN; int y = rem2 / OHx, x = rem2 % OHx;
      const float* drow = dL + b*512;
      bf16* orow;
      float nz = 0.f; const float* srow = nullptr;
      if(UP){
        orow = outp + (((size_t)((b*U + 2*y + py))*U + (2*x + px)) << 9);
      } else {
        nz = nwv * noise[(b*OHy + y)*OHx + x];
        srow = sN + b*512;
        orow = outp + ((size_t)me << 9);
      }
      #pragma unroll
      for(int nf = 0; nf < 4; nf++){
        int n = nbase + ncol0 + nf*16 + lr;
        float val = acc[mf][nf][r] * drow[n];
        if(!UP) val = lrelu_s2(val + nz + ab[n]) * srow[n];
        orow[n] = __float2bfloat16(val);
      }
    }
  }
}

// ---------------- big conv 256x256, 512 thr, 8 waves (non-UP only) -----------
// Wave = 128M x 64N (2Mx4N arrangement), acc 8x4. Same chunk body as k_conv.
// LDS bytes/FLOP 0.047 -> 0.031 => predicted MfmaUtil ~55-60%.
__global__ __launch_bounds__(512, 2)
void k_conv2(const bf16* __restrict__ act, const bf16* __restrict__ wL,
             const float* __restrict__ dL, const float* __restrict__ noise,
             const float* __restrict__ nw_ptr, const float* __restrict__ ab,
             const float* __restrict__ sN, bf16* __restrict__ outp,
             int Hin, int Mblocks){
  const int q8 = gridDim.x >> 3;
  const int swz = (blockIdx.x & 7)*q8 + (blockIdx.x >> 3);
  const int nb = swz & 1, mb = swz >> 1;
  if(mb >= Mblocks) return;
  const int mbase = mb*256, nbase = nb*256;
  const int pixN = Hin*Hin;
  const int Mtot = NB*pixN;
  if(mbase >= Mtot) return;

  __shared__ short As[256*64];                   // 32 KB
  __shared__ short Bs[256*64];                   // 32 KB
  const int t = threadIdx.x;                     // 0..511
  const int row  = t >> 1;                       // 0..255
  const int half = t & 1;
  const int r7   = row & 7;

  int m = mbase + row;
  const bool mval = (m < Mtot);
  int mm = mval ? m : 0;
  const int gb = mm / pixN; int rem = mm % pixN;
  const int gY = rem / Hin, gX = rem % Hin;

  const int wid = t >> 6;                        // 0..7
  const int mrow0 = (wid >> 2)*128;              // 0 or 128
  const int ncol0 = (wid & 3)*64;                // 0,64,128,192
  const int lr = t & 15;
  const int ks = (t & 63) >> 4;
  const int lr7 = lr & 7;
  const int sw0 = (ks ^ lr7)*8;
  const int sw1 = ((4 + ks) ^ lr7)*8;

  int wsl[4];
  #pragma unroll
  for(int j = 0; j < 4; j++) wsl[j] = ((half*4 + j) ^ r7)*8;

  f32x4 acc[8][4];
  #pragma unroll
  for(int i = 0; i < 8; i++)
    #pragma unroll
    for(int j = 0; j < 4; j++) acc[i][j] = (f32x4){0.f,0.f,0.f,0.f};

  const bf16* browB = wL + ((size_t)(nbase + row) << 9) + half*32;

  for(int tt = 0; tt < 9; tt++){
    const int dy = tt/3, dx = tt - dy*3;
    const int tap = tt;
    bool aok = false; const bf16* aptr = act;
    {
      int yy = gY + dy - 1, xx = gX + dx - 1;
      if(mval && (unsigned)yy < (unsigned)Hin && (unsigned)xx < (unsigned)Hin){
        aok = true;
        aptr = act + ((size_t)((gb*Hin + yy)*Hin + xx) << 9) + half*32;
      }
    }
    const bf16* bptr = browB + ((size_t)tap << 18);

    uint4 pa[4], pb[4];
    #pragma unroll
    for(int j = 0; j < 4; j++){
      pa[j] = aok ? *(const uint4*)(aptr + j*8) : make_uint4(0u,0u,0u,0u);
      pb[j] = *(const uint4*)(bptr + j*8);
    }

    #pragma unroll
    for(int c = 0; c < 8; c++){
      asm volatile("" ::: "memory");
      __builtin_amdgcn_s_barrier();
      #pragma unroll
      for(int j = 0; j < 4; j++){
        *(uint4*)&As[row*64 + wsl[j]] = pa[j];
        *(uint4*)&Bs[row*64 + wsl[j]] = pb[j];
      }
      uint4 na[4], nb4[4];
      if(c < 7){
        const int koff = (c+1)*64;
        #pragma unroll
        for(int j = 0; j < 4; j++){
          na[j]  = aok ? *(const uint4*)(aptr + koff + j*8) : make_uint4(0u,0u,0u,0u);
          nb4[j] = *(const uint4*)(bptr + koff + j*8);
        }
      }
      asm volatile("s_waitcnt lgkmcnt(0)" ::: "memory");
      __builtin_amdgcn_s_barrier();
      #pragma unroll
      for(int h = 0; h < 2; h++){
        const int swr = h ? sw1 : sw0;
        bf16x8 af[8], bfr[4];
        #pragma unroll
        for(int f = 0; f < 8; f++)
          af[f]  = *(const bf16x8*)&As[(mrow0 + f*16 + lr)*64 + swr];
        #pragma unroll
        for(int f = 0; f < 4; f++)
          bfr[f] = *(const bf16x8*)&Bs[(ncol0 + f*16 + lr)*64 + swr];
        #pragma unroll
        for(int mf = 0; mf < 8; mf++)
          #pragma unroll
          for(int nf = 0; nf < 4; nf++)
            acc[mf][nf] = __builtin_amdgcn_mfma_f32_16x16x32_bf16(af[mf], bfr[nf], acc[mf][nf], 0, 0, 0);
      }
      if(c < 7){
        #pragma unroll
        for(int j = 0; j < 4; j++){ pa[j] = na[j]; pb[j] = nb4[j]; }
      }
    }
  }

  const float nwv = *nw_ptr;
  #pragma unroll
  for(int mf = 0; mf < 8; mf++){
    #pragma unroll
    for(int r = 0; r < 4; r++){
      int me = mbase + mrow0 + mf*16 + ks*4 + r;
      if(me >= Mtot) continue;
      int b = me / pixN; int rem2 = me % pixN; int y = rem2 / Hin, x = rem2 % Hin;
      const float* drow = dL + b*512;
      float nz = nwv * noise[(b*Hin + y)*Hin + x];
      const float* srow = sN + b*512;
      bf16* orow = outp + ((size_t)me << 9);
      #pragma unroll
      for(int nf = 0; nf < 4; nf++){
        int n = nbase + ncol0 + nf*16 + lr;
        float val = acc[mf][nf][r] * drow[n];
        val = lrelu_s2(val + nz + ab[n]) * srow[n];
        orow[n] = __float2bfloat16(val);
      }
    }
  }
}

// ---------------- separable blur: V pass (u -> tmp) --------------------------
__global__ void k_blurV(const bf16* __restrict__ u, bf16* __restrict__ tmp, int O){
  const int U = O + 1;
  size_t gid = (size_t)blockIdx.x*256 + threadIdx.x;
  size_t total = (size_t)NB*O*U*128;
  if(gid >= total) return;
  int c4 = gid & 127;
  size_t pix = gid >> 7;                         // (b*O + Y)*U + X
  int X = pix % U; int Y = (pix/U) % O; int b = pix/((size_t)O*U);
  const float k1[4] = {0.25f, 0.75f, 0.75f, 0.25f};
  float4 a = make_float4(0.f,0.f,0.f,0.f);
  #pragma unroll
  for(int ky = 0; ky < 4; ky++){
    int yy = Y + ky - 1; if(yy < 0 || yy >= U) continue;
    float w = k1[ky];
    uint2 u2 = *(const uint2*)(u + (((size_t)(b*U + yy)*U + X) << 9) + c4*4);
    a.x += w*bf_lo(u2.x); a.y += w*bf_hi(u2.x);
    a.z += w*bf_lo(u2.y); a.w += w*bf_hi(u2.y);
  }
  uint2 pk;
  pk.x = packbf2(a.x, a.y); pk.y = packbf2(a.z, a.w);
  *(uint2*)(tmp + (pix << 9) + c4*4) = pk;
}

// ------- separable blur: H pass + noise + bias + lrelu + next-scale ----------
__global__ void k_blurH(const bf16* __restrict__ tmp, const float* __restrict__ noise,
                        const float* __restrict__ nw_ptr, const float* __restrict__ ab,
                        const float* __restrict__ sN, bf16* __restrict__ act, int O){
  const int U = O + 1;
  size_t gid = (size_t)blockIdx.x*256 + threadIdx.x;
  size_t total = (size_t)NB*O*O*128;
  if(gid >= total) return;
  int c4 = gid & 127;
  size_t pix = gid >> 7;                         // (b*O + Y)*O + X
  int X = pix % O; int Y = (pix/O) % O; int b = pix/((size_t)O*O);
  const float k1[4] = {0.25f, 0.75f, 0.75f, 0.25f};
  float4 a = make_float4(0.f,0.f,0.f,0.f);
  #pragma unroll
  for(int kx = 0; kx < 4; kx++){
    int xx = X + kx - 1; if(xx < 0 || xx >= U) continue;
    float w = k1[kx];
    uint2 u2 = *(const uint2*)(tmp + (((size_t)(b*O + Y)*U + xx) << 9) + c4*4);
    a.x += w*bf_lo(u2.x); a.y += w*bf_hi(u2.x);
    a.z += w*bf_lo(u2.y); a.w += w*bf_hi(u2.y);
  }
  float nz = (*nw_ptr) * noise[(b*O + Y)*O + X];
  const float* abp4 = ab + c4*4;
  float4 s4 = *(const float4*)(sN + b*512 + c4*4);
  uint2 pk;
  pk.x = packbf2(lrelu_s2(a.x + nz + abp4[0])*s4.x, lrelu_s2(a.y + nz + abp4[1])*s4.y);
  pk.y = packbf2(lrelu_s2(a.z + nz + abp4[2])*s4.z, lrelu_s2(a.w + nz + abp4[3])*s4.w);
  *(uint2*)(act + (pix << 9) + c4*4) = pk;
}

// ---------------- toRGB (1x1 mod conv, no demod) -> NCHW skip ----------------
__global__ void k_torgb(const bf16* __restrict__ act, const float* __restrict__ tw,
                        const float* __restrict__ ratL, const float* __restrict__ tbias,
                        float* __restrict__ dst, int H, int lt, int addflag){
  int wid = threadIdx.x >> 6, lane = threadIdx.x & 63;
  int pix = blockIdx.x*4 + wid;
  int npix = NB*H*H;
  if(pix >= npix) return;
  int b = pix/(H*H);
  const bf16* ap = act + ((size_t)pix << 9);
  const float* rp = ratL + (size_t)b*512;
  const float* w0 = tw + ((size_t)lt*3 + 0)*512;
  const float* w1 = tw + ((size_t)lt*3 + 1)*512;
  const float* w2 = tw + ((size_t)lt*3 + 2)*512;
  float a0 = 0.f, a1 = 0.f, a2 = 0.f;
  #pragma unroll
  for(int j = 0; j < 8; j++){
    int i = lane + j*64;
    float xs = __bfloat162float(ap[i])*rp[i];
    a0 += xs*w0[i]; a1 += xs*w1[i]; a2 += xs*w2[i];
  }
  for(int off = 32; off > 0; off >>= 1){
    a0 += __shfl_xor(a0, off);
    a1 += __shfl_xor(a1, off);
    a2 += __shfl_xor(a2, off);
  }
  if(lane == 0){
    int rem = pix % (H*H);
    size_t o0 = ((size_t)(b*3 + 0)*H*H) + rem;
    size_t o1 = ((size_t)(b*3 + 1)*H*H) + rem;
    size_t o2 = ((size_t)(b*3 + 2)*H*H) + rem;
    float b0 = tbias[lt*3+0], b1 = tbias[lt*3+1], b2 = tbias[lt*3+2];
    if(addflag){ dst[o0] += a0 + b0; dst[o1] += a1 + b1; dst[o2] += a2 + b2; }
    else       { dst[o0]  = a0 + b0; dst[o1]  = a1 + b1; dst[o2]  = a2 + b2; }
  }
}

// ---------------- skip upsample 2x (NCHW, 3ch) -------------------------------
__global__ void k_skipup(const float* __restrict__ sin, float* __restrict__ sout, int h){
  const int O = 2*h;
  int gid = blockIdx.x*256 + threadIdx.x;
  int total = NB*3*O*O;
  if(gid >= total) return;
  int X = gid % O; int Y = (gid/O) % O; int c = (gid/(O*O)) % 3; int b = gid/(3*O*O);
  const float k1[4] = {1.f, 3.f, 3.f, 1.f};
  float acc = 0.f;
  for(int ky = (Y & 1); ky < 4; ky += 2){
    int ty = Y + ky - 2;
    if(ty < 0) continue;
    int y = ty >> 1; if(y >= h) continue;
    for(int kx = (X & 1); kx < 4; kx += 2){
      int tx = X + kx - 2;
      if(tx < 0) continue;
      int x = tx >> 1; if(x >= h) continue;
      acc += k1[ky]*k1[kx]*(1.f/16.f) * sin[((size_t)(b*3 + c)*h + y)*h + x];
    }
  }
  sout[gid] = acc;
}

// ---------------------------------------------------------------------------
extern "C" void kernel_launch(void* const* d_in, const int* in_sizes, int n_in,
                              void* d_out, int out_size, void* d_ws, size_t ws_size,
                              hipStream_t stream){
  const float* z     = (const float*)d_in[0];
  const float* mlp_w = (const float*)d_in[1];
  const float* mlp_b = (const float*)d_in[2];
  const float* cinp  = (const float*)d_in[3];
  const float* conv_w= (const float*)d_in[4];
  const float* csw   = (const float*)d_in[5];
  const float* csb   = (const float*)d_in[6];
  const float* nwp   = (const float*)d_in[7];
  const float* abp   = (const float*)d_in[8];
  const float* tw    = (const float*)d_in[9];
  const float* tsw   = (const float*)d_in[10];
  const float* tsb   = (const float*)d_in[11];
  const float* tb    = (const float*)d_in[12];
  const float* noise[9];
  for(int i = 0; i < 9; i++) noise[i] = (const float*)d_in[13 + i];

  // workspace layout (bytes)
  const size_t UMAX = (size_t)32*65*65*512;       // 69,206,016 elems
  char* base = (char*)d_ws;
  size_t off = 0;
  bf16* buf0 = (bf16*)(base + off); off += UMAX*2;                 // 138,412,032
  bf16* buf1 = (bf16*)(base + off); off += UMAX*2;                 // 138,412,032
  bf16* wB   = (bf16*)(base + off); off += (size_t)9*9*512*512*2;  //  42,467,328
  float* wsq = (float*)(base + off); off += (size_t)9*512*512*4;   //   9,437,184
  float* wlat= (float*)(base + off); off += (size_t)32*512*4;
  float* sconv=(float*)(base + off); off += (size_t)9*32*512*4;
  float* dconv=(float*)(base + off); off += (size_t)9*32*512*4;
  float* strgb=(float*)(base + off); off += (size_t)5*32*512*4;
  float* rat  =(float*)(base + off); off += (size_t)5*32*512*4;
  float* skipA=(float*)(base + off); off += (size_t)32*3*64*64*4;
  float* skipB=(float*)(base + off); off += (size_t)32*3*64*64*4;
  if(ws_size < off){
    fprintf(stderr, "kernel_launch: ws too small (%zu < %zu)\n", ws_size, off);
    return;
  }
  float* out = (float*)d_out;

  // prep
  k_mapping<<<32, 256, 0, stream>>>(z, mlp_w, mlp_b, wlat);
  k_styles <<<896, 256, 0, stream>>>(wlat, csw, csb, tsw, tsb, sconv, strgb);
  k_prep   <<<9216, 256, 0, stream>>>(conv_w, wsq, wB);
  k_demod  <<<288, 256, 0, stream>>>(sconv, wsq, dconv);
  k_ratio  <<<320, 256, 0, stream>>>(sconv, strgb, rat);
  k_init   <<<1024, 256, 0, stream>>>(cinp, sconv, buf0);

  auto conv_noup = [&](const bf16* in, bf16* o, int H, int layer, const float* sN){
    if(H >= 32){
      int M = 32*H*H; int Mb = (M + 255)/256;
      int Gx = ((Mb*2 + 7)/8)*8;
      k_conv2<<<dim3(Gx,1,1), 512, 0, stream>>>(in, wB + ((size_t)layer*9 << 18),
          dconv + (size_t)layer*NB*512, noise[layer], nwp + layer, abp + layer*512, sN, o, H, Mb);
    } else {
      int M = 32*H*H; int Mb = (M + 127)/128;
      int Gx = ((Mb*4 + 7)/8)*8;
      k_conv<false><<<dim3(Gx,1,1), 256, 0, stream>>>(in, wB + ((size_t)layer*9 << 18),
          dconv + (size_t)layer*NB*512, noise[layer], nwp + layer, abp + layer*512, sN, o, H, Mb);
    }
  };
  auto conv_up = [&](const bf16* in, bf16* o, int Hin, int layer){
    int Mmax = 32*(Hin+1)*(Hin+1); int Mb = (Mmax + 127)/128;
    int Gx = ((Mb*4 + 7)/8)*8;
    k_conv<true><<<dim3(Gx,1,4), 256, 0, stream>>>(in, wB + ((size_t)layer*9 << 18),
        dconv + (size_t)layer*NB*512, nullptr, nullptr, nullptr, nullptr, o, Hin, Mb);
  };
  auto blur = [&](const bf16* u, bf16* tmp, bf16* o, int O, int layer, const float* sN){
    size_t totV = (size_t)32*O*(O+1)*128;
    size_t totH = (size_t)32*O*O*128;
    k_blurV<<<(unsigned)((totV + 255)/256), 256, 0, stream>>>(u, tmp, O);
    k_blurH<<<(unsigned)((totH + 255)/256), 256, 0, stream>>>(tmp, noise[layer], nwp + layer,
        abp + layer*512, sN, o, O);
  };
  auto torgb = [&](const bf16* act, float* dst, int H, int lt, int add){
    int npix = 32*H*H;
    k_torgb<<<(npix + 3)/4, 256, 0, stream>>>(act, tw, rat + (size_t)lt*NB*512, tb, dst, H, lt, add);
  };
  auto skipup = [&](const float* sin, float* sout, int h){
    int total = 32*3*(2*h)*(2*h);
    k_skipup<<<(total + 255)/256, 256, 0, stream>>>(sin, sout, h);
  };

  const float* S = sconv;   // s rows per layer: S + layer*NB*512
  const float* sT4 = strgb + (size_t)4*NB*512;

  // layer 0 @4   (buf0 = act0; output scaled by s1)
  conv_noup(buf0, buf1, 4, 0, S + (size_t)1*NB*512);   // buf0 -> buf1
  torgb(buf1, skipA, 4, 0, 0);

  // r=0: 4->8
  conv_up(buf1, buf0, 4, 1);                            // buf1 -> buf0 (u)
  blur(buf0, buf1, buf0, 8, 1, S + (size_t)2*NB*512);   // V: 0->1, H: 1->0 (act8)
  conv_noup(buf0, buf1, 8, 2, S + (size_t)3*NB*512);    // buf0 -> buf1
  skipup(skipA, skipB, 4);
  torgb(buf1, skipB, 8, 1, 1);

  // r=1: 8->16
  conv_up(buf1, buf0, 8, 3);
  blur(buf0, buf1, buf0, 16, 3, S + (size_t)4*NB*512);
  conv_noup(buf0, buf1, 16, 4, S + (size_t)5*NB*512);
  skipup(skipB, skipA, 8);
  torgb(buf1, skipA, 16, 2, 1);

  // r=2: 16->32
  conv_up(buf1, buf0, 16, 5);
  blur(buf0, buf1, buf0, 32, 5, S + (size_t)6*NB*512);
  conv_noup(buf0, buf1, 32, 6, S + (size_t)7*NB*512);
  skipup(skipA, skipB, 16);
  torgb(buf1, skipB, 32, 3, 1);

  // r=3: 32->64
  conv_up(buf1, buf0, 32, 7);
  blur(buf0, buf1, buf0, 64, 7, S + (size_t)8*NB*512);
  conv_noup(buf0, buf1, 64, 8, sT4);                    // last conv: scale by s_trgb4
  skipup(skipB, out, 32);                               // overwrite d_out (poison-safe)
  torgb(buf1, out, 64, 4, 1);                           // final skip add -> d_out
}

// Round 14
// 2129.989 us; speedup vs baseline: 2.4018x; 1.0167x over previous
//
#include <hip/hip_runtime.h>
#include <hip/hip_bf16.h>
#include <cstdio>
#include <math.h>

// ---------------------------------------------------------------------------
// StyleGANv2 generator forward. bf16 MFMA implicit-GEMM convolutions.
//   mod+demod conv == d[b,o] * conv(x * s'[b,i], w_shared); s' folded into the
//   producer epilogue so GEMM A-operand is a pure bf16 gather.
//   Up-conv: parity-decomposed (blockIdx.z = output parity class).
//   k_conv (R14): 128x128 tile, ASYNC global_load_lds double-buffered pipeline:
//   issue chunk c+1 -> LDS[buf^1], s_waitcnt vmcnt(8) (chunk c landed, c+1 in
//   flight across the barrier), raw s_barrier, MFMA, lgkmcnt(0), s_barrier.
//   No prefetch data registers -> spill-proof (R5/R9/R11 all spilled).
//   XOR-8 swizzle kept via pre-swizzled per-lane global SOURCE addresses
//   (LDS dest linear, as global_load_lds requires). Border predicates ->
//   zero-page reads (2KB zeroed ws region). 2-barrier struct ceiling was 38%
//   MfmaUtil (measured at 128^2, 256^2, B-direct); this breaks the drain.
//   Blur: separable k1 x k1 (V then H pass).
// ---------------------------------------------------------------------------

static constexpr int NB = 32;
static constexpr float SQRT2F      = 1.41421356237309515f;
static constexpr float INV_SQRT512 = 0.04419417382415922f;   // 1/sqrt(512)
static constexpr float INV_SQRT4608= 0.014731391274719742f;  // 1/sqrt(512*9)

typedef __hip_bfloat16 bf16;
typedef __attribute__((ext_vector_type(8))) short bf16x8;
typedef __attribute__((ext_vector_type(4))) float f32x4;

#define GLOAD_LDS16(src, dst) __builtin_amdgcn_global_load_lds( \
    (const __attribute__((address_space(1))) void*)(src), \
    (__attribute__((address_space(3))) void*)(dst), 16, 0, 0)

__device__ __forceinline__ float lrelu_s2(float v){ return (v > 0.f ? v : 0.2f*v) * SQRT2F; }
__device__ __forceinline__ float bf_lo(unsigned u){ unsigned v = u << 16; return __builtin_bit_cast(float, v); }
__device__ __forceinline__ float bf_hi(unsigned u){ unsigned v = u & 0xffff0000u; return __builtin_bit_cast(float, v); }
__device__ __forceinline__ unsigned packbf2(float a, float b){
  bf16 ha = __float2bfloat16(a), hb = __float2bfloat16(b);
  unsigned short ra = __builtin_bit_cast(unsigned short, ha);
  unsigned short rb = __builtin_bit_cast(unsigned short, hb);
  return (unsigned)ra | ((unsigned)rb << 16);
}

// ---------------- mapping network: pixel_norm + 8x (512x512 lrelu) ----------
__global__ void k_mapping(const float* __restrict__ z, const float* __restrict__ mlp_w,
                          const float* __restrict__ mlp_b, float* __restrict__ wlat){
  __shared__ float xb[512], yb[512], red[256];
  int b = blockIdx.x, t = threadIdx.x;
  float z0 = z[b*512 + t], z1 = z[b*512 + t + 256];
  red[t] = z0*z0 + z1*z1;
  __syncthreads();
  for(int s = 128; s > 0; s >>= 1){ if(t < s) red[t] += red[t+s]; __syncthreads(); }
  float norm = sqrtf(red[0]) * INV_SQRT512;
  float inv = 1.f / (norm + 1e-6f);
  xb[t] = z0*inv; xb[t+256] = z1*inv;
  __syncthreads();
  for(int l = 0; l < 8; l++){
    const float* Wl = mlp_w + (size_t)l*512*512;
    const float* bl = mlp_b + l*512;
    for(int oo = 0; oo < 2; oo++){
      int o = t + oo*256;
      const float4* wr = (const float4*)(Wl + (size_t)o*512);
      float acc = 0.f;
      #pragma unroll 4
      for(int k = 0; k < 128; k++){
        float4 w4 = wr[k];
        acc += w4.x*xb[4*k] + w4.y*xb[4*k+1] + w4.z*xb[4*k+2] + w4.w*xb[4*k+3];
      }
      yb[o] = lrelu_s2(acc*INV_SQRT512 + bl[o]*0.01f);
    }
    __syncthreads();
    xb[t] = yb[t]; xb[t+256] = yb[t+256];
    __syncthreads();
  }
  wlat[b*512+t] = xb[t]; wlat[b*512+t+256] = xb[t+256];
}

// ---------------- styles: s' for 9 conv layers + 5 torgb layers -------------
__global__ void k_styles(const float* __restrict__ wlat,
                         const float* __restrict__ csw, const float* __restrict__ csb,
                         const float* __restrict__ tsw, const float* __restrict__ tsb,
                         float* __restrict__ s_conv, float* __restrict__ s_trgb){
  int gid = blockIdx.x*256 + threadIdx.x;        // 14*32*512 = 229376 exactly
  int l = gid >> 14;
  int b = (gid >> 9) & 31;
  int i = gid & 511;
  const float* row; float bias, wsc;
  if(l < 9){ row = csw + ((size_t)l*512 + i)*512; bias = csb[l*512+i]; wsc = INV_SQRT4608; }
  else     { int lt = l-9; row = tsw + ((size_t)lt*512 + i)*512; bias = tsb[lt*512+i]; wsc = INV_SQRT512; }
  const float4* r4 = (const float4*)row;
  const float4* w4 = (const float4*)(wlat + b*512);
  float acc = 0.f;
  #pragma unroll 4
  for(int k = 0; k < 128; k++){
    float4 a = w4[k], c = r4[k];
    acc += a.x*c.x + a.y*c.y + a.z*c.z + a.w*c.w;
  }
  float s = (acc*INV_SQRT512 + bias) * wsc;
  if(l < 9) s_conv[((size_t)l*32 + b)*512 + i] = s;
  else      s_trgb[((size_t)(l-9)*32 + b)*512 + i] = s;
}

// ---------------- fused: wsq[l,o,i] = sum w^2; wB[l][tap][o][i] = bf16(w) ----
__global__ void k_prep(const float* __restrict__ cw, float* __restrict__ wsq,
                       bf16* __restrict__ wB){
  int gid = blockIdx.x*256 + threadIdx.x;        // 9*512*512; (l,o,i)
  const float* p = cw + (size_t)gid*9;
  int l = gid >> 18;
  int oi = gid & 0x3ffff;                        // o*512 + i
  float v[9]; float a = 0.f;
  #pragma unroll
  for(int t = 0; t < 9; t++){ v[t] = p[t]; a += v[t]*v[t]; }
  wsq[gid] = a;
  #pragma unroll
  for(int tap = 0; tap < 9; tap++)
    wB[((size_t)(l*9 + tap) << 18) + oi] = __float2bfloat16(v[tap]);
}

// ---------------- demod d[l,b,o] ---------------------------------------------
__global__ void k_demod(const float* __restrict__ s_conv, const float* __restrict__ wsq,
                        float* __restrict__ d_conv){
  __shared__ float s2[512];
  int l = blockIdx.x/32, b = blockIdx.x%32, t = threadIdx.x;
  size_t base = ((size_t)l*32 + b)*512;
  float v0 = s_conv[base + t], v1 = s_conv[base + t + 256];
  s2[t] = v0*v0; s2[t+256] = v1*v1;
  __syncthreads();
  for(int oo = 0; oo < 2; oo++){
    int o = t + oo*256;
    const float4* wr = (const float4*)(wsq + ((size_t)l*512 + o)*512);
    float acc = 0.f;
    #pragma unroll 4
    for(int k = 0; k < 128; k++){
      float4 w = wr[k];
      acc += w.x*s2[4*k] + w.y*s2[4*k+1] + w.z*s2[4*k+2] + w.w*s2[4*k+3];
    }
    d_conv[base + o] = rsqrtf(acc + 1e-8f);
  }
}

// ---------------- torgb compensation ratio ----------------------------------
__global__ void k_ratio(const float* __restrict__ s_conv, const float* __restrict__ s_trgb,
                        float* __restrict__ rat){
  int gid = blockIdx.x*256 + threadIdx.x;        // 5*32*512 = 81920
  int lt = gid >> 14;
  if(lt >= 4){ rat[gid] = 1.0f; return; }
  int b = (gid >> 9) & 31;
  int i = gid & 511;
  int cl = 1 + 2*lt;                             // consuming conv layer
  float st = s_trgb[((size_t)lt*32 + b)*512 + i];
  float sc = s_conv[((size_t)cl*32 + b)*512 + i];
  rat[gid] = (sc != 0.f) ? st/sc : 0.f;
}

// ---------------- const input -> act0 (B,4,4,512) pre-scaled by s_conv[0] ----
__global__ void k_init(const float* __restrict__ ci, const float* __restrict__ s_conv,
                       bf16* __restrict__ act){
  int gid = blockIdx.x*256 + threadIdx.x;        // 32*16*512 = 262144
  int c = gid & 511; int px = (gid >> 9) & 15; int b = gid >> 13;
  act[gid] = __float2bfloat16(ci[c*16 + px] * s_conv[b*512 + c]);
}

// ---------------- main conv: async global_load_lds pipeline ------------------
template<bool UP>
__global__ __launch_bounds__(256, 2)
void k_conv(const bf16* __restrict__ act, const bf16* __restrict__ wL,
            const float* __restrict__ dL, const float* __restrict__ noise,
            const float* __restrict__ nw_ptr, const float* __restrict__ ab,
            const float* __restrict__ sN, bf16* __restrict__ outp,
            const bf16* __restrict__ zp, int Hin, int Mblocks){
  // n-inner 1D grid + bijective XCD swizzle (gridDim.x is a multiple of 8)
  const int q8 = gridDim.x >> 3;
  const int swzb = (blockIdx.x & 7)*q8 + (blockIdx.x >> 3);
  const int nb = swzb & 3, mb = swzb >> 2;
  if(mb >= Mblocks) return;
  const int mbase = mb*128, nbase = nb*128;

  int py = 0, px = 0;
  int OHy, OHx;
  if(UP){
    int cls = blockIdx.z; py = cls >> 1; px = cls & 1;
    OHy = Hin + 1 - py; OHx = Hin + 1 - px;
  } else {
    OHy = Hin; OHx = Hin;
  }
  const int pixN = OHy*OHx;
  const int Mtot = NB*pixN;
  if(mbase >= Mtot) return;

  // LDS: double-buffered A and B, 128 rows x 128B each (linear dest for DMA;
  // swizzle folded into the per-lane global SOURCE address).
  __shared__ short As[2][128*64];
  __shared__ short Bs[2][128*64];
  const int t = threadIdx.x;
  const int wid  = t >> 6;
  const int lane = t & 63;
  const int rloc = lane >> 3;                    // row within 8-row group
  const int slot = lane & 7;                     // 16B slot within row

  // per-instruction (i=0..3) row assignment: r = wid*32 + i*8 + rloc
  int swz[4]; int gbv[4], gYv[4], gXv[4]; bool mv[4];
  const bf16* bB[4];
  #pragma unroll
  for(int i = 0; i < 4; i++){
    int r = wid*32 + i*8 + rloc;
    swz[i] = slot ^ (r & 7);
    int m = mbase + r; mv[i] = (m < Mtot); int mm = mv[i] ? m : 0;
    gbv[i] = mm / pixN; int rem = mm % pixN; gYv[i] = rem / OHx; gXv[i] = rem % OHx;
    bB[i] = wL + ((size_t)(nbase + r) << 9) + swz[i]*8;
  }

  // wave fragment geometry (4 waves, 2x2 over 128x128)
  const int mrow0 = (wid >> 1)*64;
  const int ncol0 = (wid & 1)*64;
  const int lr = t & 15;
  const int ks = (t & 63) >> 4;
  const int lr7 = lr & 7;
  const int sw0 = (ks ^ lr7)*8;
  const int sw1 = ((4 + ks) ^ lr7)*8;

  f32x4 acc[4][4];
  #pragma unroll
  for(int i = 0; i < 4; i++)
    #pragma unroll
    for(int j = 0; j < 4; j++) acc[i][j] = (f32x4){0.f,0.f,0.f,0.f};

  // tap lists (parity-valid subset for UP; all 9 otherwise)
  int dyl[3], dxl[3], ndy, ndx;
  if(UP){
    if(py == 0){ dyl[0]=0; dyl[1]=2; ndy=2; } else { dyl[0]=1; ndy=1; }
    if(px == 0){ dxl[0]=0; dxl[1]=2; ndx=2; } else { dxl[0]=1; ndx=1; }
  } else {
    dyl[0]=0; dyl[1]=1; dyl[2]=2; ndy=3;
    dxl[0]=0; dxl[1]=1; dxl[2]=2; ndx=3;
  }
  const int TT = ndy*ndx;

  // A address maker for a tap: valid -> swizzled source; invalid -> zero page
  auto mkA = [&](int dy, int dx, const bf16** aA){
    #pragma unroll
    for(int i = 0; i < 4; i++){
      int yy, xx;
      if(UP){ yy = gYv[i] - ((dy - py) >> 1); xx = gXv[i] - ((dx - px) >> 1); }
      else  { yy = gYv[i] + dy - 1;           xx = gXv[i] + dx - 1; }
      bool ok = mv[i] && ((unsigned)yy < (unsigned)Hin) && ((unsigned)xx < (unsigned)Hin);
      aA[i] = ok ? (act + (((size_t)((gbv[i]*Hin + yy)*Hin + xx)) << 9) + swz[i]*8) : zp;
    }
  };
  auto issue = [&](const bf16** aA, int tapIdx, int c, int bb){
    #pragma unroll
    for(int i = 0; i < 4; i++)
      GLOAD_LDS16(aA[i] + c*64, &As[bb][(wid*32 + i*8)*64]);
    #pragma unroll
    for(int i = 0; i < 4; i++)
      GLOAD_LDS16(bB[i] + ((size_t)tapIdx << 18) + c*64, &Bs[bb][(wid*32 + i*8)*64]);
  };

  const bf16* aC[4]; const bf16* aN[4];
  int tapC = dyl[0]*3 + dxl[0], tapN = 0;
  mkA(dyl[0], dxl[0], aC);
  issue(aC, tapC, 0, 0);                         // prologue: chunk0 -> buf0

  for(int tt = 0; tt < TT; tt++){
    const bool haveNextTap = (tt + 1 < TT);
    if(haveNextTap){
      int dyN = dyl[(tt+1)/ndx], dxN = dxl[(tt+1)%ndx];
      tapN = dyN*3 + dxN;
      mkA(dyN, dxN, aN);
    }
    #pragma unroll
    for(int c = 0; c < 8; c++){
      const int bb = c & 1;
      // issue chunk c+1 into the other buffer (crosses tap at c==7)
      bool issued = true;
      if(c < 7)               issue(aC, tapC, c+1, bb^1);
      else if(haveNextTap)    issue(aN, tapN, 0,   bb^1);
      else                    issued = false;
      if(issued) asm volatile("s_waitcnt vmcnt(8)" ::: "memory");
      else       asm volatile("s_waitcnt vmcnt(0)" ::: "memory");
      __builtin_amdgcn_s_barrier();              // chunk c ready in LDS[bb]
      #pragma unroll
      for(int h = 0; h < 2; h++){
        const int swr = h ? sw1 : sw0;
        bf16x8 af[4], bfr[4];
        #pragma unroll
        for(int f = 0; f < 4; f++){
          af[f]  = *(const bf16x8*)&As[bb][(mrow0 + f*16 + lr)*64 + swr];
          bfr[f] = *(const bf16x8*)&Bs[bb][(ncol0 + f*16 + lr)*64 + swr];
        }
        #pragma unroll
        for(int mf = 0; mf < 4; mf++)
          #pragma unroll
          for(int nf = 0; nf < 4; nf++)
            acc[mf][nf] = __builtin_amdgcn_mfma_f32_16x16x32_bf16(af[mf], bfr[nf], acc[mf][nf], 0, 0, 0);
      }
      asm volatile("s_waitcnt lgkmcnt(0)" ::: "memory");  // my LDS reads done
      __builtin_amdgcn_s_barrier();              // buf[bb] reusable next iter
    }
    if(haveNextTap){
      #pragma unroll
      for(int i = 0; i < 4; i++) aC[i] = aN[i];
      tapC = tapN;
    }
  }

  // epilogue: C/D frag mapping col=lane&15, row=(lane>>4)*4+reg  [m89-verified]
  const float nwv = UP ? 0.f : *nw_ptr;
  const int U = 2*Hin + 1;
  #pragma unroll
  for(int mf = 0; mf < 4; mf++){
    #pragma unroll
    for(int r = 0; r < 4; r++){
      int me = mbase + mrow0 + mf*16 + ks*4 + r;
      if(me >= Mtot) continue;
      int b = me / pixN; int rem2 = me % pixN; int y = rem2 / OHx, x = rem2 % OHx;
      const float* drow = dL + b*512;
      bf16* orow;
      float nz = 0.f; const float* srow = nullptr;
      if(UP){
        orow = outp + (((size_t)((b*U + 2*y + py))*U + (2*x + px)) << 9);
      } else {
        nz = nwv * noise[(b*OHy + y)*OHx + x];
        srow = sN + b*512;
        orow = outp + ((size_t)me << 9);
      }
      #pragma unroll
      for(int nf = 0; nf < 4; nf++){
        int n = nbase + ncol0 + nf*16 + lr;
        float val = acc[mf][nf][r] * drow[n];
        if(!UP) val = lrelu_s2(val + nz + ab[n]) * srow[n];
        orow[n] = __float2bfloat16(val);
      }
    }
  }
}

// ---------------- separable blur: V pass (u -> tmp) --------------------------
__global__ void k_blurV(const bf16* __restrict__ u, bf16* __restrict__ tmp, int O){
  const int U = O + 1;
  size_t gid = (size_t)blockIdx.x*256 + threadIdx.x;
  size_t total = (size_t)NB*O*U*128;
  if(gid >= total) return;
  int c4 = gid & 127;
  size_t pix = gid >> 7;                         // (b*O + Y)*U + X
  int X = pix % U; int Y = (pix/U) % O; int b = pix/((size_t)O*U);
  const float k1[4] = {0.25f, 0.75f, 0.75f, 0.25f};
  float4 a = make_float4(0.f,0.f,0.f,0.f);
  #pragma unroll
  for(int ky = 0; ky < 4; ky++){
    int yy = Y + ky - 1; if(yy < 0 || yy >= U) continue;
    float w = k1[ky];
    uint2 u2 = *(const uint2*)(u + (((size_t)(b*U + yy)*U + X) << 9) + c4*4);
    a.x += w*bf_lo(u2.x); a.y += w*bf_hi(u2.x);
    a.z += w*bf_lo(u2.y); a.w += w*bf_hi(u2.y);
  }
  uint2 pk;
  pk.x = packbf2(a.x, a.y); pk.y = packbf2(a.z, a.w);
  *(uint2*)(tmp + (pix << 9) + c4*4) = pk;
}

// ------- separable blur: H pass + noise + bias + lrelu + next-scale ----------
__global__ void k_blurH(const bf16* __restrict__ tmp, const float* __restrict__ noise,
                        const float* __restrict__ nw_ptr, const float* __restrict__ ab,
                        const float* __restrict__ sN, bf16* __restrict__ act, int O){
  const int U = O + 1;
  size_t gid = (size_t)blockIdx.x*256 + threadIdx.x;
  size_t total = (size_t)NB*O*O*128;
  if(gid >= total) return;
  int c4 = gid & 127;
  size_t pix = gid >> 7;                         // (b*O + Y)*O + X
  int X = pix % O; int Y = (pix/O) % O; int b = pix/((size_t)O*O);
  const float k1[4] = {0.25f, 0.75f, 0.75f, 0.25f};
  float4 a = make_float4(0.f,0.f,0.f,0.f);
  #pragma unroll
  for(int kx = 0; kx < 4; kx++){
    int xx = X + kx - 1; if(xx < 0 || xx >= U) continue;
    float w = k1[kx];
    uint2 u2 = *(const uint2*)(tmp + (((size_t)(b*O + Y)*U + xx) << 9) + c4*4);
    a.x += w*bf_lo(u2.x); a.y += w*bf_hi(u2.x);
    a.z += w*bf_lo(u2.y); a.w += w*bf_hi(u2.y);
  }
  float nz = (*nw_ptr) * noise[(b*O + Y)*O + X];
  const float* abp4 = ab + c4*4;
  float4 s4 = *(const float4*)(sN + b*512 + c4*4);
  uint2 pk;
  pk.x = packbf2(lrelu_s2(a.x + nz + abp4[0])*s4.x, lrelu_s2(a.y + nz + abp4[1])*s4.y);
  pk.y = packbf2(lrelu_s2(a.z + nz + abp4[2])*s4.z, lrelu_s2(a.w + nz + abp4[3])*s4.w);
  *(uint2*)(act + (pix << 9) + c4*4) = pk;
}

// ---------------- toRGB (1x1 mod conv, no demod) -> NCHW skip ----------------
__global__ void k_torgb(const bf16* __restrict__ act, const float* __restrict__ tw,
                        const float* __restrict__ ratL, const float* __restrict__ tbias,
                        float* __restrict__ dst, int H, int lt, int addflag){
  int wid = threadIdx.x >> 6, lane = threadIdx.x & 63;
  int pix = blockIdx.x*4 + wid;
  int npix = NB*H*H;
  if(pix >= npix) return;
  int b = pix/(H*H);
  const bf16* ap = act + ((size_t)pix << 9);
  const float* rp = ratL + (size_t)b*512;
  const float* w0 = tw + ((size_t)lt*3 + 0)*512;
  const float* w1 = tw + ((size_t)lt*3 + 1)*512;
  const float* w2 = tw + ((size_t)lt*3 + 2)*512;
  float a0 = 0.f, a1 = 0.f, a2 = 0.f;
  #pragma unroll
  for(int j = 0; j < 8; j++){
    int i = lane + j*64;
    float xs = __bfloat162float(ap[i])*rp[i];
    a0 += xs*w0[i]; a1 += xs*w1[i]; a2 += xs*w2[i];
  }
  for(int off = 32; off > 0; off >>= 1){
    a0 += __shfl_xor(a0, off);
    a1 += __shfl_xor(a1, off);
    a2 += __shfl_xor(a2, off);
  }
  if(lane == 0){
    int rem = pix % (H*H);
    size_t o0 = ((size_t)(b*3 + 0)*H*H) + rem;
    size_t o1 = ((size_t)(b*3 + 1)*H*H) + rem;
    size_t o2 = ((size_t)(b*3 + 2)*H*H) + rem;
    float b0 = tbias[lt*3+0], b1 = tbias[lt*3+1], b2 = tbias[lt*3+2];
    if(addflag){ dst[o0] += a0 + b0; dst[o1] += a1 + b1; dst[o2] += a2 + b2; }
    else       { dst[o0]  = a0 + b0; dst[o1]  = a1 + b1; dst[o2]  = a2 + b2; }
  }
}

// ---------------- skip upsample 2x (NCHW, 3ch) -------------------------------
__global__ void k_skipup(const float* __restrict__ sin, float* __restrict__ sout, int h){
  const int O = 2*h;
  int gid = blockIdx.x*256 + threadIdx.x;
  int total = NB*3*O*O;
  if(gid >= total) return;
  int X = gid % O; int Y = (gid/O) % O; int c = (gid/(O*O)) % 3; int b = gid/(3*O*O);
  const float k1[4] = {1.f, 3.f, 3.f, 1.f};
  float acc = 0.f;
  for(int ky = (Y & 1); ky < 4; ky += 2){
    int ty = Y + ky - 2;
    if(ty < 0) continue;
    int y = ty >> 1; if(y >= h) continue;
    for(int kx = (X & 1); kx < 4; kx += 2){
      int tx = X + kx - 2;
      if(tx < 0) continue;
      int x = tx >> 1; if(x >= h) continue;
      acc += k1[ky]*k1[kx]*(1.f/16.f) * sin[((size_t)(b*3 + c)*h + y)*h + x];
    }
  }
  sout[gid] = acc;
}

// ---------------------------------------------------------------------------
extern "C" void kernel_launch(void* const* d_in, const int* in_sizes, int n_in,
                              void* d_out, int out_size, void* d_ws, size_t ws_size,
                              hipStream_t stream){
  const float* z     = (const float*)d_in[0];
  const float* mlp_w = (const float*)d_in[1];
  const float* mlp_b = (const float*)d_in[2];
  const float* cinp  = (const float*)d_in[3];
  const float* conv_w= (const float*)d_in[4];
  const float* csw   = (const float*)d_in[5];
  const float* csb   = (const float*)d_in[6];
  const float* nwp   = (const float*)d_in[7];
  const float* abp   = (const float*)d_in[8];
  const float* tw    = (const float*)d_in[9];
  const float* tsw   = (const float*)d_in[10];
  const float* tsb   = (const float*)d_in[11];
  const float* tb    = (const float*)d_in[12];
  const float* noise[9];
  for(int i = 0; i < 9; i++) noise[i] = (const float*)d_in[13 + i];

  // workspace layout (bytes)
  const size_t UMAX = (size_t)32*65*65*512;       // 69,206,016 elems
  char* base = (char*)d_ws;
  size_t off = 0;
  bf16* buf0 = (bf16*)(base + off); off += UMAX*2;                 // 138,412,032
  bf16* buf1 = (bf16*)(base + off); off += UMAX*2;                 // 138,412,032
  bf16* wB   = (bf16*)(base + off); off += (size_t)9*9*512*512*2;  //  42,467,328
  float* wsq = (float*)(base + off); off += (size_t)9*512*512*4;   //   9,437,184
  float* wlat= (float*)(base + off); off += (size_t)32*512*4;
  float* sconv=(float*)(base + off); off += (size_t)9*32*512*4;
  float* dconv=(float*)(base + off); off += (size_t)9*32*512*4;
  float* strgb=(float*)(base + off); off += (size_t)5*32*512*4;
  float* rat  =(float*)(base + off); off += (size_t)5*32*512*4;
  float* skipA=(float*)(base + off); off += (size_t)32*3*64*64*4;
  float* skipB=(float*)(base + off); off += (size_t)32*3*64*64*4;
  bf16* zpage=(bf16*)(base + off); off += 2048;                    // zero page
  if(ws_size < off){
    fprintf(stderr, "kernel_launch: ws too small (%zu < %zu)\n", ws_size, off);
    return;
  }
  float* out = (float*)d_out;

  // prep
  hipMemsetAsync(zpage, 0, 2048, stream);
  k_mapping<<<32, 256, 0, stream>>>(z, mlp_w, mlp_b, wlat);
  k_styles <<<896, 256, 0, stream>>>(wlat, csw, csb, tsw, tsb, sconv, strgb);
  k_prep   <<<9216, 256, 0, stream>>>(conv_w, wsq, wB);
  k_demod  <<<288, 256, 0, stream>>>(sconv, wsq, dconv);
  k_ratio  <<<320, 256, 0, stream>>>(sconv, strgb, rat);
  k_init   <<<1024, 256, 0, stream>>>(cinp, sconv, buf0);

  auto conv_noup = [&](const bf16* in, bf16* o, int H, int layer, const float* sN){
    int M = 32*H*H; int Mb = (M + 127)/128;
    int Gx = ((Mb*4 + 7)/8)*8;
    k_conv<false><<<dim3(Gx,1,1), 256, 0, stream>>>(in, wB + ((size_t)layer*9 << 18),
        dconv + (size_t)layer*NB*512, noise[layer], nwp + layer, abp + layer*512, sN, o, zpage, H, Mb);
  };
  auto conv_up = [&](const bf16* in, bf16* o, int Hin, int layer){
    int Mmax = 32*(Hin+1)*(Hin+1); int Mb = (Mmax + 127)/128;
    int Gx = ((Mb*4 + 7)/8)*8;
    k_conv<true><<<dim3(Gx,1,4), 256, 0, stream>>>(in, wB + ((size_t)layer*9 << 18),
        dconv + (size_t)layer*NB*512, nullptr, nullptr, nullptr, nullptr, o, zpage, Hin, Mb);
  };
  auto blur = [&](const bf16* u, bf16* tmp, bf16* o, int O, int layer, const float* sN){
    size_t totV = (size_t)32*O*(O+1)*128;
    size_t totH = (size_t)32*O*O*128;
    k_blurV<<<(unsigned)((totV + 255)/256), 256, 0, stream>>>(u, tmp, O);
    k_blurH<<<(unsigned)((totH + 255)/256), 256, 0, stream>>>(tmp, noise[layer], nwp + layer,
        abp + layer*512, sN, o, O);
  };
  auto torgb = [&](const bf16* act, float* dst, int H, int lt, int add){
    int npix = 32*H*H;
    k_torgb<<<(npix + 3)/4, 256, 0, stream>>>(act, tw, rat + (size_t)lt*NB*512, tb, dst, H, lt, add);
  };
  auto skipup = [&](const float* sin, float* sout, int h){
    int total = 32*3*(2*h)*(2*h);
    k_skipup<<<(total + 255)/256, 256, 0, stream>>>(sin, sout, h);
  };

  const float* S = sconv;   // s rows per layer: S + layer*NB*512
  const float* sT4 = strgb + (size_t)4*NB*512;

  // layer 0 @4   (buf0 = act0; output scaled by s1)
  conv_noup(buf0, buf1, 4, 0, S + (size_t)1*NB*512);   // buf0 -> buf1
  torgb(buf1, skipA, 4, 0, 0);

  // r=0: 4->8
  conv_up(buf1, buf0, 4, 1);                            // buf1 -> buf0 (u)
  blur(buf0, buf1, buf0, 8, 1, S + (size_t)2*NB*512);   // V: 0->1, H: 1->0 (act8)
  conv_noup(buf0, buf1, 8, 2, S + (size_t)3*NB*512);    // buf0 -> buf1
  skipup(skipA, skipB, 4);
  torgb(buf1, skipB, 8, 1, 1);

  // r=1: 8->16
  conv_up(buf1, buf0, 8, 3);
  blur(buf0, buf1, buf0, 16, 3, S + (size_t)4*NB*512);
  conv_noup(buf0, buf1, 16, 4, S + (size_t)5*NB*512);
  skipup(skipB, skipA, 8);
  torgb(buf1, skipA, 16, 2, 1);

  // r=2: 16->32
  conv_up(buf1, buf0, 16, 5);
  blur(buf0, buf1, buf0, 32, 5, S + (size_t)6*NB*512);
  conv_noup(buf0, buf1, 32, 6, S + (size_t)7*NB*512);
  skipup(skipA, skipB, 16);
  torgb(buf1, skipB, 32, 3, 1);

  // r=3: 32->64
  conv_up(buf1, buf0, 32, 7);
  blur(buf0, buf1, buf0, 64, 7, S + (size_t)8*NB*512);
  conv_noup(buf0, buf1, 64, 8, sT4);                    // last conv: scale by s_trgb4
  skipup(skipB, out, 32);                               // overwrite d_out (poison-safe)
  torgb(buf1, out, 64, 4, 1);                           // final skip add -> d_out
}

// Round 15
// 2106.191 us; speedup vs baseline: 2.4289x; 1.0113x over previous
//
#include <hip/hip_runtime.h>
#include <hip/hip_bf16.h>
#include <cstdio>
#include <math.h>

// ---------------------------------------------------------------------------
// StyleGANv2 generator forward. bf16 MFMA implicit-GEMM convolutions.
//   mod+demod conv == d[b,o] * conv(x * s'[b,i], w_shared); s' folded into the
//   producer epilogue so GEMM A-operand is a pure bf16 gather.
//   Up-conv: parity-decomposed (blockIdx.z = output parity class).
//   k_conv (R14+T5): 128x128 tile, ASYNC global_load_lds double-buffered
//   pipeline (issue chunk c+1 -> LDS[buf^1], vmcnt(8) counted wait, raw
//   s_barrier, MFMA wrapped in s_setprio(1/0), lgkmcnt(0), s_barrier).
//   No prefetch data registers -> spill-proof. XOR-8 swizzle via pre-swizzled
//   per-lane global SOURCE addresses; border predicates -> zero-page reads.
//   k_blurF: fused separable blur (V pass -> LDS row buffer -> H pass +
//   noise/bias/lrelu/next-scale) — kills the tmp tensor round-trip.
// ---------------------------------------------------------------------------

static constexpr int NB = 32;
static constexpr float SQRT2F      = 1.41421356237309515f;
static constexpr float INV_SQRT512 = 0.04419417382415922f;   // 1/sqrt(512)
static constexpr float INV_SQRT4608= 0.014731391274719742f;  // 1/sqrt(512*9)

typedef __hip_bfloat16 bf16;
typedef __attribute__((ext_vector_type(8))) short bf16x8;
typedef __attribute__((ext_vector_type(4))) float f32x4;

#define GLOAD_LDS16(src, dst) __builtin_amdgcn_global_load_lds( \
    (const __attribute__((address_space(1))) void*)(src), \
    (__attribute__((address_space(3))) void*)(dst), 16, 0, 0)

__device__ __forceinline__ float lrelu_s2(float v){ return (v > 0.f ? v : 0.2f*v) * SQRT2F; }
__device__ __forceinline__ float bf_lo(unsigned u){ unsigned v = u << 16; return __builtin_bit_cast(float, v); }
__device__ __forceinline__ float bf_hi(unsigned u){ unsigned v = u & 0xffff0000u; return __builtin_bit_cast(float, v); }
__device__ __forceinline__ unsigned packbf2(float a, float b){
  bf16 ha = __float2bfloat16(a), hb = __float2bfloat16(b);
  unsigned short ra = __builtin_bit_cast(unsigned short, ha);
  unsigned short rb = __builtin_bit_cast(unsigned short, hb);
  return (unsigned)ra | ((unsigned)rb << 16);
}

// ---------------- mapping network: pixel_norm + 8x (512x512 lrelu) ----------
__global__ void k_mapping(const float* __restrict__ z, const float* __restrict__ mlp_w,
                          const float* __restrict__ mlp_b, float* __restrict__ wlat){
  __shared__ float xb[512], yb[512], red[256];
  int b = blockIdx.x, t = threadIdx.x;
  float z0 = z[b*512 + t], z1 = z[b*512 + t + 256];
  red[t] = z0*z0 + z1*z1;
  __syncthreads();
  for(int s = 128; s > 0; s >>= 1){ if(t < s) red[t] += red[t+s]; __syncthreads(); }
  float norm = sqrtf(red[0]) * INV_SQRT512;
  float inv = 1.f / (norm + 1e-6f);
  xb[t] = z0*inv; xb[t+256] = z1*inv;
  __syncthreads();
  for(int l = 0; l < 8; l++){
    const float* Wl = mlp_w + (size_t)l*512*512;
    const float* bl = mlp_b + l*512;
    for(int oo = 0; oo < 2; oo++){
      int o = t + oo*256;
      const float4* wr = (const float4*)(Wl + (size_t)o*512);
      float acc = 0.f;
      #pragma unroll 4
      for(int k = 0; k < 128; k++){
        float4 w4 = wr[k];
        acc += w4.x*xb[4*k] + w4.y*xb[4*k+1] + w4.z*xb[4*k+2] + w4.w*xb[4*k+3];
      }
      yb[o] = lrelu_s2(acc*INV_SQRT512 + bl[o]*0.01f);
    }
    __syncthreads();
    xb[t] = yb[t]; xb[t+256] = yb[t+256];
    __syncthreads();
  }
  wlat[b*512+t] = xb[t]; wlat[b*512+t+256] = xb[t+256];
}

// ---------------- styles: s' for 9 conv layers + 5 torgb layers -------------
__global__ void k_styles(const float* __restrict__ wlat,
                         const float* __restrict__ csw, const float* __restrict__ csb,
                         const float* __restrict__ tsw, const float* __restrict__ tsb,
                         float* __restrict__ s_conv, float* __restrict__ s_trgb){
  int gid = blockIdx.x*256 + threadIdx.x;        // 14*32*512 = 229376 exactly
  int l = gid >> 14;
  int b = (gid >> 9) & 31;
  int i = gid & 511;
  const float* row; float bias, wsc;
  if(l < 9){ row = csw + ((size_t)l*512 + i)*512; bias = csb[l*512+i]; wsc = INV_SQRT4608; }
  else     { int lt = l-9; row = tsw + ((size_t)lt*512 + i)*512; bias = tsb[lt*512+i]; wsc = INV_SQRT512; }
  const float4* r4 = (const float4*)row;
  const float4* w4 = (const float4*)(wlat + b*512);
  float acc = 0.f;
  #pragma unroll 4
  for(int k = 0; k < 128; k++){
    float4 a = w4[k], c = r4[k];
    acc += a.x*c.x + a.y*c.y + a.z*c.z + a.w*c.w;
  }
  float s = (acc*INV_SQRT512 + bias) * wsc;
  if(l < 9) s_conv[((size_t)l*32 + b)*512 + i] = s;
  else      s_trgb[((size_t)(l-9)*32 + b)*512 + i] = s;
}

// ---------------- fused: wsq[l,o,i] = sum w^2; wB[l][tap][o][i] = bf16(w) ----
__global__ void k_prep(const float* __restrict__ cw, float* __restrict__ wsq,
                       bf16* __restrict__ wB){
  int gid = blockIdx.x*256 + threadIdx.x;        // 9*512*512; (l,o,i)
  const float* p = cw + (size_t)gid*9;
  int l = gid >> 18;
  int oi = gid & 0x3ffff;                        // o*512 + i
  float v[9]; float a = 0.f;
  #pragma unroll
  for(int t = 0; t < 9; t++){ v[t] = p[t]; a += v[t]*v[t]; }
  wsq[gid] = a;
  #pragma unroll
  for(int tap = 0; tap < 9; tap++)
    wB[((size_t)(l*9 + tap) << 18) + oi] = __float2bfloat16(v[tap]);
}

// ---------------- demod d[l,b,o] ---------------------------------------------
__global__ void k_demod(const float* __restrict__ s_conv, const float* __restrict__ wsq,
                        float* __restrict__ d_conv){
  __shared__ float s2[512];
  int l = blockIdx.x/32, b = blockIdx.x%32, t = threadIdx.x;
  size_t base = ((size_t)l*32 + b)*512;
  float v0 = s_conv[base + t], v1 = s_conv[base + t + 256];
  s2[t] = v0*v0; s2[t+256] = v1*v1;
  __syncthreads();
  for(int oo = 0; oo < 2; oo++){
    int o = t + oo*256;
    const float4* wr = (const float4*)(wsq + ((size_t)l*512 + o)*512);
    float acc = 0.f;
    #pragma unroll 4
    for(int k = 0; k < 128; k++){
      float4 w = wr[k];
      acc += w.x*s2[4*k] + w.y*s2[4*k+1] + w.z*s2[4*k+2] + w.w*s2[4*k+3];
    }
    d_conv[base + o] = rsqrtf(acc + 1e-8f);
  }
}

// ---------------- torgb compensation ratio ----------------------------------
__global__ void k_ratio(const float* __restrict__ s_conv, const float* __restrict__ s_trgb,
                        float* __restrict__ rat){
  int gid = blockIdx.x*256 + threadIdx.x;        // 5*32*512 = 81920
  int lt = gid >> 14;
  if(lt >= 4){ rat[gid] = 1.0f; return; }
  int b = (gid >> 9) & 31;
  int i = gid & 511;
  int cl = 1 + 2*lt;                             // consuming conv layer
  float st = s_trgb[((size_t)lt*32 + b)*512 + i];
  float sc = s_conv[((size_t)cl*32 + b)*512 + i];
  rat[gid] = (sc != 0.f) ? st/sc : 0.f;
}

// ---------------- const input -> act0 (B,4,4,512) pre-scaled by s_conv[0] ----
__global__ void k_init(const float* __restrict__ ci, const float* __restrict__ s_conv,
                       bf16* __restrict__ act){
  int gid = blockIdx.x*256 + threadIdx.x;        // 32*16*512 = 262144
  int c = gid & 511; int px = (gid >> 9) & 15; int b = gid >> 13;
  act[gid] = __float2bfloat16(ci[c*16 + px] * s_conv[b*512 + c]);
}

// ---------------- main conv: async global_load_lds pipeline + setprio --------
template<bool UP>
__global__ __launch_bounds__(256, 2)
void k_conv(const bf16* __restrict__ act, const bf16* __restrict__ wL,
            const float* __restrict__ dL, const float* __restrict__ noise,
            const float* __restrict__ nw_ptr, const float* __restrict__ ab,
            const float* __restrict__ sN, bf16* __restrict__ outp,
            const bf16* __restrict__ zp, int Hin, int Mblocks){
  // n-inner 1D grid + bijective XCD swizzle (gridDim.x is a multiple of 8)
  const int q8 = gridDim.x >> 3;
  const int swzb = (blockIdx.x & 7)*q8 + (blockIdx.x >> 3);
  const int nb = swzb & 3, mb = swzb >> 2;
  if(mb >= Mblocks) return;
  const int mbase = mb*128, nbase = nb*128;

  int py = 0, px = 0;
  int OHy, OHx;
  if(UP){
    int cls = blockIdx.z; py = cls >> 1; px = cls & 1;
    OHy = Hin + 1 - py; OHx = Hin + 1 - px;
  } else {
    OHy = Hin; OHx = Hin;
  }
  const int pixN = OHy*OHx;
  const int Mtot = NB*pixN;
  if(mbase >= Mtot) return;

  // LDS: double-buffered A and B, 128 rows x 128B each (linear dest for DMA;
  // swizzle folded into the per-lane global SOURCE address).
  __shared__ short As[2][128*64];
  __shared__ short Bs[2][128*64];
  const int t = threadIdx.x;
  const int wid  = t >> 6;
  const int lane = t & 63;
  const int rloc = lane >> 3;                    // row within 8-row group
  const int slot = lane & 7;                     // 16B slot within row

  // per-instruction (i=0..3) row assignment: r = wid*32 + i*8 + rloc
  int swz[4]; int gbv[4], gYv[4], gXv[4]; bool mv[4];
  const bf16* bB[4];
  #pragma unroll
  for(int i = 0; i < 4; i++){
    int r = wid*32 + i*8 + rloc;
    swz[i] = slot ^ (r & 7);
    int m = mbase + r; mv[i] = (m < Mtot); int mm = mv[i] ? m : 0;
    gbv[i] = mm / pixN; int rem = mm % pixN; gYv[i] = rem / OHx; gXv[i] = rem % OHx;
    bB[i] = wL + ((size_t)(nbase + r) << 9) + swz[i]*8;
  }

  // wave fragment geometry (4 waves, 2x2 over 128x128)
  const int mrow0 = (wid >> 1)*64;
  const int ncol0 = (wid & 1)*64;
  const int lr = t & 15;
  const int ks = (t & 63) >> 4;
  const int lr7 = lr & 7;
  const int sw0 = (ks ^ lr7)*8;
  const int sw1 = ((4 + ks) ^ lr7)*8;

  f32x4 acc[4][4];
  #pragma unroll
  for(int i = 0; i < 4; i++)
    #pragma unroll
    for(int j = 0; j < 4; j++) acc[i][j] = (f32x4){0.f,0.f,0.f,0.f};

  // tap lists (parity-valid subset for UP; all 9 otherwise)
  int dyl[3], dxl[3], ndy, ndx;
  if(UP){
    if(py == 0){ dyl[0]=0; dyl[1]=2; ndy=2; } else { dyl[0]=1; ndy=1; }
    if(px == 0){ dxl[0]=0; dxl[1]=2; ndx=2; } else { dxl[0]=1; ndx=1; }
  } else {
    dyl[0]=0; dyl[1]=1; dyl[2]=2; ndy=3;
    dxl[0]=0; dxl[1]=1; dxl[2]=2; ndx=3;
  }
  const int TT = ndy*ndx;

  // A address maker for a tap: valid -> swizzled source; invalid -> zero page
  auto mkA = [&](int dy, int dx, const bf16** aA){
    #pragma unroll
    for(int i = 0; i < 4; i++){
      int yy, xx;
      if(UP){ yy = gYv[i] - ((dy - py) >> 1); xx = gXv[i] - ((dx - px) >> 1); }
      else  { yy = gYv[i] + dy - 1;           xx = gXv[i] + dx - 1; }
      bool ok = mv[i] && ((unsigned)yy < (unsigned)Hin) && ((unsigned)xx < (unsigned)Hin);
      aA[i] = ok ? (act + (((size_t)((gbv[i]*Hin + yy)*Hin + xx)) << 9) + swz[i]*8) : zp;
    }
  };
  auto issue = [&](const bf16** aA, int tapIdx, int c, int bb){
    #pragma unroll
    for(int i = 0; i < 4; i++)
      GLOAD_LDS16(aA[i] + c*64, &As[bb][(wid*32 + i*8)*64]);
    #pragma unroll
    for(int i = 0; i < 4; i++)
      GLOAD_LDS16(bB[i] + ((size_t)tapIdx << 18) + c*64, &Bs[bb][(wid*32 + i*8)*64]);
  };

  const bf16* aC[4]; const bf16* aN[4];
  int tapC = dyl[0]*3 + dxl[0], tapN = 0;
  mkA(dyl[0], dxl[0], aC);
  issue(aC, tapC, 0, 0);                         // prologue: chunk0 -> buf0

  for(int tt = 0; tt < TT; tt++){
    const bool haveNextTap = (tt + 1 < TT);
    if(haveNextTap){
      int dyN = dyl[(tt+1)/ndx], dxN = dxl[(tt+1)%ndx];
      tapN = dyN*3 + dxN;
      mkA(dyN, dxN, aN);
    }
    #pragma unroll
    for(int c = 0; c < 8; c++){
      const int bb = c & 1;
      // issue chunk c+1 into the other buffer (crosses tap at c==7)
      bool issued = true;
      if(c < 7)               issue(aC, tapC, c+1, bb^1);
      else if(haveNextTap)    issue(aN, tapN, 0,   bb^1);
      else                    issued = false;
      if(issued) asm volatile("s_waitcnt vmcnt(8)" ::: "memory");
      else       asm volatile("s_waitcnt vmcnt(0)" ::: "memory");
      __builtin_amdgcn_s_barrier();              // chunk c ready in LDS[bb]
      #pragma unroll
      for(int h = 0; h < 2; h++){
        const int swr = h ? sw1 : sw0;
        bf16x8 af[4], bfr[4];
        #pragma unroll
        for(int f = 0; f < 4; f++){
          af[f]  = *(const bf16x8*)&As[bb][(mrow0 + f*16 + lr)*64 + swr];
          bfr[f] = *(const bf16x8*)&Bs[bb][(ncol0 + f*16 + lr)*64 + swr];
        }
        __builtin_amdgcn_s_setprio(1);           // T5: favor MFMA cluster
        #pragma unroll
        for(int mf = 0; mf < 4; mf++)
          #pragma unroll
          for(int nf = 0; nf < 4; nf++)
            acc[mf][nf] = __builtin_amdgcn_mfma_f32_16x16x32_bf16(af[mf], bfr[nf], acc[mf][nf], 0, 0, 0);
        __builtin_amdgcn_s_setprio(0);
      }
      asm volatile("s_waitcnt lgkmcnt(0)" ::: "memory");  // my LDS reads done
      __builtin_amdgcn_s_barrier();              // buf[bb] reusable next iter
    }
    if(haveNextTap){
      #pragma unroll
      for(int i = 0; i < 4; i++) aC[i] = aN[i];
      tapC = tapN;
    }
  }

  // epilogue: C/D frag mapping col=lane&15, row=(lane>>4)*4+reg  [m89-verified]
  const float nwv = UP ? 0.f : *nw_ptr;
  const int U = 2*Hin + 1;
  #pragma unroll
  for(int mf = 0; mf < 4; mf++){
    #pragma unroll
    for(int r = 0; r < 4; r++){
      int me = mbase + mrow0 + mf*16 + ks*4 + r;
      if(me >= Mtot) continue;
      int b = me / pixN; int rem2 = me % pixN; int y = rem2 / OHx, x = rem2 % OHx;
      const float* drow = dL + b*512;
      bf16* orow;
      float nz = 0.f; const float* srow = nullptr;
      if(UP){
        orow = outp + (((size_t)((b*U + 2*y + py))*U + (2*x + px)) << 9);
      } else {
        nz = nwv * noise[(b*OHy + y)*OHx + x];
        srow = sN + b*512;
        orow = outp + ((size_t)me << 9);
      }
      #pragma unroll
      for(int nf = 0; nf < 4; nf++){
        int n = nbase + ncol0 + nf*16 + lr;
        float val = acc[mf][nf][r] * drow[n];
        if(!UP) val = lrelu_s2(val + nz + ab[n]) * srow[n];
        orow[n] = __float2bfloat16(val);
      }
    }
  }
}

// ------ fused separable blur: V pass -> LDS row buffer -> H pass + epilogue --
// One block per (b, Y, channel-quarter of 128). vrow holds the V result for
// all U columns of this output row. Numerically identical to V->tmp->H
// (same bf16 rounding point between passes).
__global__ void k_blurF(const bf16* __restrict__ u, const float* __restrict__ noise,
                        const float* __restrict__ nw_ptr, const float* __restrict__ ab,
                        const float* __restrict__ sN, bf16* __restrict__ act, int O){
  const int U = O + 1;
  __shared__ unsigned vrow[65*64];               // U x 64 uint (128 bf16 ch)
  const int bid = blockIdx.x;
  const int cq = bid & 3;
  const int rowid = bid >> 2;
  const int Y = rowid % O; const int b = rowid / O;
  const int t = threadIdx.x;
  const int ch2 = t & 63;                        // uint lane within 128-ch set
  const int cg  = t >> 6;                        // column group 0..3
  const float k1[4] = {0.25f, 0.75f, 0.75f, 0.25f};

  // V pass: vrow[col] = sum_ky k1[ky] * u[b][Y+ky-1][col][cq*128 + 2ch]
  for(int it = 0; it < (65 + 3)/4; it++){
    int col = it*4 + cg;
    if(col < U){
      float a0 = 0.f, a1 = 0.f;
      #pragma unroll
      for(int ky = 0; ky < 4; ky++){
        int yy = Y + ky - 1; if(yy < 0 || yy >= U) continue;
        unsigned uv = *(const unsigned*)(u + (((size_t)(b*U + yy)*U + col) << 9) + cq*128 + ch2*2);
        a0 += k1[ky]*bf_lo(uv); a1 += k1[ky]*bf_hi(uv);
      }
      vrow[col*64 + ch2] = packbf2(a0, a1);
    }
  }
  __syncthreads();
  // H pass + noise + bias + lrelu + next-scale
  const float nwv = *nw_ptr;
  const float abA = ab[cq*128 + ch2*2], abB = ab[cq*128 + ch2*2 + 1];
  const float sA  = sN[b*512 + cq*128 + ch2*2], sB = sN[b*512 + cq*128 + ch2*2 + 1];
  for(int it = 0; it < (64 + 3)/4; it++){
    int X = it*4 + cg;
    if(X < O){
      float a0 = 0.f, a1 = 0.f;
      #pragma unroll
      for(int kx = 0; kx < 4; kx++){
        int xx = X + kx - 1; if(xx < 0 || xx >= U) continue;
        unsigned v = vrow[xx*64 + ch2];
        a0 += k1[kx]*bf_lo(v); a1 += k1[kx]*bf_hi(v);
      }
      float nz = nwv * noise[(b*O + Y)*O + X];
      unsigned pk = packbf2(lrelu_s2(a0 + nz + abA)*sA, lrelu_s2(a1 + nz + abB)*sB);
      *(unsigned*)(act + (((size_t)(b*O + Y)*O + X) << 9) + cq*128 + ch2*2) = pk;
    }
  }
}

// ---------------- toRGB (1x1 mod conv, no demod) -> NCHW skip ----------------
__global__ void k_torgb(const bf16* __restrict__ act, const float* __restrict__ tw,
                        const float* __restrict__ ratL, const float* __restrict__ tbias,
                        float* __restrict__ dst, int H, int lt, int addflag){
  int wid = threadIdx.x >> 6, lane = threadIdx.x & 63;
  int pix = blockIdx.x*4 + wid;
  int npix = NB*H*H;
  if(pix >= npix) return;
  int b = pix/(H*H);
  const bf16* ap = act + ((size_t)pix << 9);
  const float* rp = ratL + (size_t)b*512;
  const float* w0 = tw + ((size_t)lt*3 + 0)*512;
  const float* w1 = tw + ((size_t)lt*3 + 1)*512;
  const float* w2 = tw + ((size_t)lt*3 + 2)*512;
  float a0 = 0.f, a1 = 0.f, a2 = 0.f;
  #pragma unroll
  for(int j = 0; j < 8; j++){
    int i = lane + j*64;
    float xs = __bfloat162float(ap[i])*rp[i];
    a0 += xs*w0[i]; a1 += xs*w1[i]; a2 += xs*w2[i];
  }
  for(int off = 32; off > 0; off >>= 1){
    a0 += __shfl_xor(a0, off);
    a1 += __shfl_xor(a1, off);
    a2 += __shfl_xor(a2, off);
  }
  if(lane == 0){
    int rem = pix % (H*H);
    size_t o0 = ((size_t)(b*3 + 0)*H*H) + rem;
    size_t o1 = ((size_t)(b*3 + 1)*H*H) + rem;
    size_t o2 = ((size_t)(b*3 + 2)*H*H) + rem;
    float b0 = tbias[lt*3+0], b1 = tbias[lt*3+1], b2 = tbias[lt*3+2];
    if(addflag){ dst[o0] += a0 + b0; dst[o1] += a1 + b1; dst[o2] += a2 + b2; }
    else       { dst[o0]  = a0 + b0; dst[o1]  = a1 + b1; dst[o2]  = a2 + b2; }
  }
}

// ---------------- skip upsample 2x (NCHW, 3ch) -------------------------------
__global__ void k_skipup(const float* __restrict__ sin, float* __restrict__ sout, int h){
  const int O = 2*h;
  int gid = blockIdx.x*256 + threadIdx.x;
  int total = NB*3*O*O;
  if(gid >= total) return;
  int X = gid % O; int Y = (gid/O) % O; int c = (gid/(O*O)) % 3; int b = gid/(3*O*O);
  const float k1[4] = {1.f, 3.f, 3.f, 1.f};
  float acc = 0.f;
  for(int ky = (Y & 1); ky < 4; ky += 2){
    int ty = Y + ky - 2;
    if(ty < 0) continue;
    int y = ty >> 1; if(y >= h) continue;
    for(int kx = (X & 1); kx < 4; kx += 2){
      int tx = X + kx - 2;
      if(tx < 0) continue;
      int x = tx >> 1; if(x >= h) continue;
      acc += k1[ky]*k1[kx]*(1.f/16.f) * sin[((size_t)(b*3 + c)*h + y)*h + x];
    }
  }
  sout[gid] = acc;
}

// ---------------------------------------------------------------------------
extern "C" void kernel_launch(void* const* d_in, const int* in_sizes, int n_in,
                              void* d_out, int out_size, void* d_ws, size_t ws_size,
                              hipStream_t stream){
  const float* z     = (const float*)d_in[0];
  const float* mlp_w = (const float*)d_in[1];
  const float* mlp_b = (const float*)d_in[2];
  const float* cinp  = (const float*)d_in[3];
  const float* conv_w= (const float*)d_in[4];
  const float* csw   = (const float*)d_in[5];
  const float* csb   = (const float*)d_in[6];
  const float* nwp   = (const float*)d_in[7];
  const float* abp   = (const float*)d_in[8];
  const float* tw    = (const float*)d_in[9];
  const float* tsw   = (const float*)d_in[10];
  const float* tsb   = (const float*)d_in[11];
  const float* tb    = (const float*)d_in[12];
  const float* noise[9];
  for(int i = 0; i < 9; i++) noise[i] = (const float*)d_in[13 + i];

  // workspace layout (bytes)
  const size_t UMAX = (size_t)32*65*65*512;       // 69,206,016 elems
  char* base = (char*)d_ws;
  size_t off = 0;
  bf16* buf0 = (bf16*)(base + off); off += UMAX*2;                 // 138,412,032
  bf16* buf1 = (bf16*)(base + off); off += UMAX*2;                 // 138,412,032
  bf16* wB   = (bf16*)(base + off); off += (size_t)9*9*512*512*2;  //  42,467,328
  float* wsq = (float*)(base + off); off += (size_t)9*512*512*4;   //   9,437,184
  float* wlat= (float*)(base + off); off += (size_t)32*512*4;
  float* sconv=(float*)(base + off); off += (size_t)9*32*512*4;
  float* dconv=(float*)(base + off); off += (size_t)9*32*512*4;
  float* strgb=(float*)(base + off); off += (size_t)5*32*512*4;
  float* rat  =(float*)(base + off); off += (size_t)5*32*512*4;
  float* skipA=(float*)(base + off); off += (size_t)32*3*64*64*4;
  float* skipB=(float*)(base + off); off += (size_t)32*3*64*64*4;
  bf16* zpage=(bf16*)(base + off); off += 2048;                    // zero page
  if(ws_size < off){
    fprintf(stderr, "kernel_launch: ws too small (%zu < %zu)\n", ws_size, off);
    return;
  }
  float* out = (float*)d_out;

  // prep
  hipMemsetAsync(zpage, 0, 2048, stream);
  k_mapping<<<32, 256, 0, stream>>>(z, mlp_w, mlp_b, wlat);
  k_styles <<<896, 256, 0, stream>>>(wlat, csw, csb, tsw, tsb, sconv, strgb);
  k_prep   <<<9216, 256, 0, stream>>>(conv_w, wsq, wB);
  k_demod  <<<288, 256, 0, stream>>>(sconv, wsq, dconv);
  k_ratio  <<<320, 256, 0, stream>>>(sconv, strgb, rat);
  k_init   <<<1024, 256, 0, stream>>>(cinp, sconv, buf0);

  auto conv_noup = [&](const bf16* in, bf16* o, int H, int layer, const float* sN){
    int M = 32*H*H; int Mb = (M + 127)/128;
    int Gx = ((Mb*4 + 7)/8)*8;
    k_conv<false><<<dim3(Gx,1,1), 256, 0, stream>>>(in, wB + ((size_t)layer*9 << 18),
        dconv + (size_t)layer*NB*512, noise[layer], nwp + layer, abp + layer*512, sN, o, zpage, H, Mb);
  };
  auto conv_up = [&](const bf16* in, bf16* o, int Hin, int layer){
    int Mmax = 32*(Hin+1)*(Hin+1); int Mb = (Mmax + 127)/128;
    int Gx = ((Mb*4 + 7)/8)*8;
    k_conv<true><<<dim3(Gx,1,4), 256, 0, stream>>>(in, wB + ((size_t)layer*9 << 18),
        dconv + (size_t)layer*NB*512, nullptr, nullptr, nullptr, nullptr, o, zpage, Hin, Mb);
  };
  auto blur = [&](const bf16* u, bf16* o, int O, int layer, const float* sN){
    int blocks = 32*O*4;
    k_blurF<<<blocks, 256, 0, stream>>>(u, noise[layer], nwp + layer,
        abp + layer*512, sN, o, O);
  };
  auto torgb = [&](const bf16* act, float* dst, int H, int lt, int add){
    int npix = 32*H*H;
    k_torgb<<<(npix + 3)/4, 256, 0, stream>>>(act, tw, rat + (size_t)lt*NB*512, tb, dst, H, lt, add);
  };
  auto skipup = [&](const float* sin, float* sout, int h){
    int total = 32*3*(2*h)*(2*h);
    k_skipup<<<(total + 255)/256, 256, 0, stream>>>(sin, sout, h);
  };

  const float* S = sconv;   // s rows per layer: S + layer*NB*512
  const float* sT4 = strgb + (size_t)4*NB*512;

  // layer 0 @4   (buf0 = act0; output scaled by s1)
  conv_noup(buf0, buf1, 4, 0, S + (size_t)1*NB*512);   // buf0 -> buf1
  torgb(buf1, skipA, 4, 0, 0);

  // r=0: 4->8
  conv_up(buf1, buf0, 4, 1);                            // buf1 -> buf0 (u)
  blur(buf0, buf1, 8, 1, S + (size_t)2*NB*512);         // buf0 -> buf1 (act8)
  conv_noup(buf1, buf0, 8, 2, S + (size_t)3*NB*512);    // buf1 -> buf0
  skipup(skipA, skipB, 4);
  torgb(buf0, skipB, 8, 1, 1);

  // r=1: 8->16
  conv_up(buf0, buf1, 8, 3);
  blur(buf1, buf0, 16, 3, S + (size_t)4*NB*512);
  conv_noup(buf0, buf1, 16, 4, S + (size_t)5*NB*512);
  skipup(skipB, skipA, 8);
  torgb(buf1, skipA, 16, 2, 1);

  // r=2: 16->32
  conv_up(buf1, buf0, 16, 5);
  blur(buf0, buf1, 32, 5, S + (size_t)6*NB*512);
  conv_noup(buf1, buf0, 32, 6, S + (size_t)7*NB*512);
  skipup(skipA, skipB, 16);
  torgb(buf0, skipB, 32, 3, 1);

  // r=3: 32->64
  conv_up(buf0, buf1, 32, 7);
  blur(buf1, buf0, 64, 7, S + (size_t)8*NB*512);
  conv_noup(buf0, buf1, 64, 8, sT4);                    // last conv: scale by s_trgb4
  skipup(skipB, out, 32);                               // overwrite d_out (poison-safe)
  torgb(buf1, out, 64, 4, 1);                           // final skip add -> d_out
}